// Round 6
// baseline (1339.157 us; speedup 1.0000x reference)
//
#include <hip/hip_runtime.h>

#define NN   100000
#define NE   1600000
#define CIN  128
#define K2   256
#define COUT 128

typedef __attribute__((ext_vector_type(8))) short bf16x8;
typedef __attribute__((ext_vector_type(4))) float f32x4;

__device__ __forceinline__ ushort f2bf(float f) {
    union { float f; unsigned u; } v; v.f = f;
    unsigned r = (v.u + 0x7FFFu + ((v.u >> 16) & 1u)) >> 16;
    return (ushort)r;
}
__device__ __forceinline__ float bflo(unsigned p) {
    union { unsigned u; float f; } v; v.u = p << 16; return v.f;
}
__device__ __forceinline__ float bfhi(unsigned p) {
    union { unsigned u; float f; } v; v.u = p & 0xFFFF0000u; return v.f;
}

// ======================= V3: atomic-free binned pipeline =======================

#define NB1      49        // coarse bins: dst>>11 (2048 nodes each)
#define CAP1     40960     // records per coarse bin (mean 32.7K, +46 sigma)
#define NF       1568      // fine-bin slots (49*32); used: dst>>6 <= 1562
#define CAP2     1536      // records per fine bin (mean 1024, +16 sigma)
#define LCAP1    120       // LDS staging cap, bin1 (mean 63.8, +7 sigma + net)
#define LCAP2    160       // LDS staging cap, bin2 (mean 64, +12 sigma + net)
#define NBIN1BLK 512
#define E1       3125      // NE / NBIN1BLK
#define NGEMMB   784       // 128 rows each -> 100352 >= NN

// ---- W f32 -> bf16 (one-time tiny kernel) ----
__global__ __launch_bounds__(256) void k_castw(const float* __restrict__ w,
                                               ushort* __restrict__ wb) {
    int i = blockIdx.x * 256 + threadIdx.x;       // [0, 8192)
    float4 v = *reinterpret_cast<const float4*>(w + (size_t)i * 4);
    ushort4 r; r.x = f2bf(v.x); r.y = f2bf(v.y); r.z = f2bf(v.z); r.w = f2bf(v.w);
    *reinterpret_cast<ushort4*>(wb + (size_t)i * 4) = r;
}

// ---- fused: dual GEMM (yh = x@Wh^T bf16, out = x@Wx^T + bias f32) || BIN1 ----
__global__ __launch_bounds__(256) void k_p1(const float* __restrict__ x,
                                            const ushort* __restrict__ wb,
                                            const float* __restrict__ bias,
                                            const int* __restrict__ esrc,
                                            const int* __restrict__ edst,
                                            int* __restrict__ gctr1,
                                            int2* __restrict__ gbin1,
                                            ushort* __restrict__ yh,
                                            float* __restrict__ out) {
    __shared__ int  lcnt[64];
    __shared__ int  lbase[64];
    __shared__ int2 lbuf[NB1 * LCAP1];    // 47 KB

    int b = blockIdx.x, t = threadIdx.x;
    bool isGemm; int rb;
    if (b < 1024) { isGemm = ((b & 1) == 0); rb = b >> 1; }
    else          { isGemm = true;           rb = 512 + (b - 1024); }

    if (isGemm) {
        int wid = t >> 6, lane = t & 63;
        int lr = lane & 15, lk = lane >> 4;
        int row0 = rb * 128 + wid * 32;
        #pragma unroll 1
        for (int pass = 0; pass < 2; ++pass) {
            int wko = pass * CIN;            // Wh: k in [0,128), Wx: [128,256)
            f32x4 acc[2][8];
            #pragma unroll
            for (int m = 0; m < 2; ++m)
                #pragma unroll
                for (int n = 0; n < 8; ++n) acc[m][n] = (f32x4)0.f;

            #pragma unroll
            for (int kb = 0; kb < 4; ++kb) {
                int kofs = kb * 32 + lk * 8;
                bf16x8 a[2];
                #pragma unroll
                for (int m = 0; m < 2; ++m) {
                    int r = row0 + m * 16 + lr; if (r >= NN) r = NN - 1;
                    const float* xp = x + (size_t)r * CIN + kofs;
                    float4 u0 = *reinterpret_cast<const float4*>(xp);
                    float4 u1 = *reinterpret_cast<const float4*>(xp + 4);
                    bf16x8 aa;
                    aa[0] = (short)f2bf(u0.x); aa[1] = (short)f2bf(u0.y);
                    aa[2] = (short)f2bf(u0.z); aa[3] = (short)f2bf(u0.w);
                    aa[4] = (short)f2bf(u1.x); aa[5] = (short)f2bf(u1.y);
                    aa[6] = (short)f2bf(u1.z); aa[7] = (short)f2bf(u1.w);
                    a[m] = aa;
                }
                #pragma unroll
                for (int n = 0; n < 8; ++n) {
                    bf16x8 bfr = *reinterpret_cast<const bf16x8*>(
                        wb + (size_t)(n * 16 + lr) * K2 + wko + kofs);
                    acc[0][n] = __builtin_amdgcn_mfma_f32_16x16x32_bf16(a[0], bfr, acc[0][n], 0, 0, 0);
                    acc[1][n] = __builtin_amdgcn_mfma_f32_16x16x32_bf16(a[1], bfr, acc[1][n], 0, 0, 0);
                }
            }
            if (pass == 0) {
                #pragma unroll
                for (int m = 0; m < 2; ++m)
                    #pragma unroll
                    for (int j = 0; j < 4; ++j) {
                        int r = row0 + m * 16 + lk * 4 + j;
                        if (r < NN) {
                            #pragma unroll
                            for (int n = 0; n < 8; ++n)
                                yh[(size_t)r * CIN + n * 16 + lr] = f2bf(acc[m][n][j]);
                        }
                    }
            } else {
                float bv[8];
                #pragma unroll
                for (int n = 0; n < 8; ++n) bv[n] = bias[n * 16 + lr];
                #pragma unroll
                for (int m = 0; m < 2; ++m)
                    #pragma unroll
                    for (int j = 0; j < 4; ++j) {
                        int r = row0 + m * 16 + lk * 4 + j;
                        if (r < NN) {
                            #pragma unroll
                            for (int n = 0; n < 8; ++n)
                                out[(size_t)r * COUT + n * 16 + lr] = acc[m][n][j] + bv[n];
                        }
                    }
            }
        }
    } else {
        // ---- BIN1: LDS-staged coarse binning, ~49 global atomics per block ----
        int base = rb * E1;
        for (int i = t; i < 64; i += 256) lcnt[i] = 0;
        __syncthreads();
        for (int e = t; e < E1; e += 256) {
            int d = edst[base + e], s = esrc[base + e];
            int c = d >> 11;
            int p = atomicAdd(&lcnt[c], 1);
            if (p < LCAP1) lbuf[c * LCAP1 + p] = make_int2(d, s);
            else {                                  // overflow net (≈never)
                int gp = atomicAdd(&gctr1[c], 1);
                if (gp < CAP1) gbin1[(size_t)c * CAP1 + gp] = make_int2(d, s);
            }
        }
        __syncthreads();
        if (t < NB1) {
            int n = lcnt[t]; if (n > LCAP1) n = LCAP1;
            lbase[t] = atomicAdd(&gctr1[t], n);
            lcnt[t] = n;
        }
        __syncthreads();
        for (int c = 0; c < NB1; ++c) {
            int n = lcnt[c], g0 = lbase[c];
            for (int i = t; i < n; i += 256)
                if (g0 + i < CAP1)
                    gbin1[(size_t)c * CAP1 + g0 + i] = lbuf[c * LCAP1 + i];
        }
    }
}

// ---- BIN2: coarse -> fine (64-node) bins ----
__global__ __launch_bounds__(256) void k_p2(const int* __restrict__ gctr1,
                                            const int2* __restrict__ gbin1,
                                            int* __restrict__ gctr2,
                                            int2* __restrict__ gbin2) {
    __shared__ int  lcnt[32];
    __shared__ int  lbase[32];
    __shared__ int2 lbuf[32 * LCAP2];     // 40 KB
    int c = blockIdx.x >> 4;              // 0..48
    int j = blockIdx.x & 15;              // 16 blocks per coarse bin
    int t = threadIdx.x;
    int cnt = gctr1[c]; if (cnt > CAP1) cnt = CAP1;
    int share = (cnt + 15) >> 4;
    int lo = j * share, hi = min(cnt, lo + share);
    if (t < 32) lcnt[t] = 0;
    __syncthreads();
    for (int i = lo + t; i < hi; i += 256) {
        int2 r = gbin1[(size_t)c * CAP1 + i];
        int fl = (r.x >> 6) & 31;
        int p = atomicAdd(&lcnt[fl], 1);
        if (p < LCAP2) lbuf[fl * LCAP2 + p] = r;
        else {
            int f = (c << 5) + fl;
            int gp = atomicAdd(&gctr2[f], 1);
            if (gp < CAP2) gbin2[(size_t)f * CAP2 + gp] = r;
        }
    }
    __syncthreads();
    if (t < 32) {
        int n = lcnt[t]; if (n > LCAP2) n = LCAP2;
        lbase[t] = atomicAdd(&gctr2[(c << 5) + t], n);
        lcnt[t] = n;
    }
    __syncthreads();
    for (int fl = 0; fl < 32; ++fl) {
        int n = lcnt[fl], g0 = lbase[fl];
        size_t fb = (size_t)((c << 5) + fl) * CAP2;
        for (int i = t; i < n; i += 256)
            if (g0 + i < CAP2) gbin2[fb + g0 + i] = lbuf[fl * LCAP2 + i];
    }
}

// ---- agg + combine: out[n] += (sum yh[src]) / deg, per fine bin ----
__global__ __launch_bounds__(256) void k_p3(const int* __restrict__ gctr2,
                                            const int2* __restrict__ gbin2,
                                            const ushort* __restrict__ yh,
                                            float* __restrict__ out) {
    __shared__ float acc[64 * 128];       // 32 KB
    __shared__ int   deg[64];
    int f = blockIdx.x, t = threadIdx.x;
    int wid = t >> 6, lane = t & 63;
    for (int i = t; i < 64 * 128; i += 256) acc[i] = 0.f;
    if (t < 64) deg[t] = 0;
    __syncthreads();

    int m = gctr2[f]; if (m > CAP2) m = CAP2;
    const int2* recs = gbin2 + (size_t)f * CAP2;
    int shr = (m + 3) >> 2;
    int lo = wid * shr, hi = min(m, lo + shr);

    for (int base = lo; base < hi; base += 64) {
        int nrec = hi - base; if (nrec > 64) nrec = 64;
        int2 myrec = make_int2(0, 0);
        if (base + lane < hi) myrec = recs[base + lane];
        for (int j = 0; j < nrec; j += 8) {
            int kk = nrec - j; if (kk > 8) kk = 8;
            unsigned v[8]; int nd[8];
            #pragma unroll
            for (int k = 0; k < 8; ++k) {
                if (k < kk) {
                    int d = __shfl(myrec.x, j + k);
                    int s = __shfl(myrec.y, j + k);
                    nd[k] = d & 63;
                    v[k] = *reinterpret_cast<const unsigned*>(yh + (size_t)s * CIN + lane * 2);
                } else { nd[k] = -1; v[k] = 0; }
            }
            #pragma unroll
            for (int k = 0; k < 8; ++k) {
                if (nd[k] >= 0) {
                    atomicAdd(&acc[nd[k] * 128 + lane * 2],     bflo(v[k]));
                    atomicAdd(&acc[nd[k] * 128 + lane * 2 + 1], bfhi(v[k]));
                    if (lane == 0) atomicAdd(&deg[nd[k]], 1);
                }
            }
        }
    }
    __syncthreads();

    int node0 = f << 6;
    for (int i = wid; i < 64; i += 4) {
        int n = node0 + i;
        if (n >= NN) break;
        int dg = deg[i];
        float inv = dg > 0 ? 1.0f / (float)dg : 0.0f;
        size_t o = (size_t)n * COUT + lane;
        out[o]      += acc[i * 128 + lane]      * inv;
        out[o + 64] += acc[i * 128 + 64 + lane] * inv;
    }
}

// ======================= V2 fallback (round-5, validated) =======================

#define NXCD  8
#define PART  ((NN + NXCD - 1) / NXCD)
#define NB_SCAT  2048
#define NB_CAST  12500
#define NB_CASTW 32
#define CAP  64

__global__ __launch_bounds__(256) void k_fuse2(const float* __restrict__ x,
                                               const float* __restrict__ w,
                                               const int* __restrict__ src,
                                               const int* __restrict__ dst,
                                               int* __restrict__ cnt,
                                               int* __restrict__ csrF,
                                               ushort* hcat,
                                               ushort* __restrict__ wb) {
    int b = blockIdx.x, t = threadIdx.x;
    if (b < NB_SCAT) {
        int part = b & (NXCD - 1);
        int slot = b >> 3;
        int lo = part * PART;
        int hi = lo + PART; if (hi > NN) hi = NN;
        const int NCH = NE / 4;
        for (int c = slot * 256 + t; c < NCH; c += 256 * 256) {
            int4 d = *reinterpret_cast<const int4*>(dst + (size_t)c * 4);
            int4 s = *reinterpret_cast<const int4*>(src + (size_t)c * 4);
            if (d.x >= lo && d.x < hi) { int p = atomicAdd(&cnt[d.x], 1); csrF[(d.x << 6) + p] = s.x; }
            if (d.y >= lo && d.y < hi) { int p = atomicAdd(&cnt[d.y], 1); csrF[(d.y << 6) + p] = s.y; }
            if (d.z >= lo && d.z < hi) { int p = atomicAdd(&cnt[d.z], 1); csrF[(d.z << 6) + p] = s.z; }
            if (d.w >= lo && d.w < hi) { int p = atomicAdd(&cnt[d.w], 1); csrF[(d.w << 6) + p] = s.w; }
        }
    } else if (b < NB_SCAT + NB_CAST) {
        int i = (b - NB_SCAT) * 256 + t;
        int node = i >> 5, c4 = (i & 31) * 4;
        float4 v = *reinterpret_cast<const float4*>(x + (size_t)node * CIN + c4);
        ushort4 r; r.x = f2bf(v.x); r.y = f2bf(v.y); r.z = f2bf(v.z); r.w = f2bf(v.w);
        *reinterpret_cast<ushort4*>(hcat + (size_t)node * K2 + CIN + c4) = r;
    } else {
        int i = (b - NB_SCAT - NB_CAST) * 256 + t;
        float4 v = *reinterpret_cast<const float4*>(w + (size_t)i * 4);
        ushort4 r; r.x = f2bf(v.x); r.y = f2bf(v.y); r.z = f2bf(v.z); r.w = f2bf(v.w);
        *reinterpret_cast<ushort4*>(wb + (size_t)i * 4) = r;
    }
}

__global__ __launch_bounds__(256) void k_aggB(const int* __restrict__ cnt,
                                              const int* __restrict__ csrF,
                                              ushort* hcat) {
    int gw   = (blockIdx.x * 256 + threadIdx.x) >> 6;
    int lane = threadIdx.x & 63;
    if (gw >= NN) return;
    int gws = __builtin_amdgcn_readfirstlane(gw);
    int deg = cnt[gws];
    const int4* b4 = reinterpret_cast<const int4*>(csrF + ((size_t)gws << 6));
    int boff = CIN + lane * 2;
    float ax = 0.f, ay = 0.f;
    for (int e = 0; e < deg; e += 8) {
        int4 c0 = b4[(e >> 2)];
        int4 c1 = b4[(e >> 2) + 1];
        int ss[8] = {c0.x, c0.y, c0.z, c0.w, c1.x, c1.y, c1.z, c1.w};
        #pragma unroll
        for (int k = 0; k < 8; ++k) {
            bool ok = (e + k) < deg;
            int s = ok ? ss[k] : 0;
            unsigned v = *reinterpret_cast<const unsigned*>(hcat + ((size_t)s << 8) + boff);
            float mq = ok ? 1.f : 0.f;
            ax += mq * bflo(v); ay += mq * bfhi(v);
        }
    }
    float inv = (deg > 0) ? 1.0f / (float)deg : 0.0f;
    unsigned packed = (unsigned)f2bf(ax * inv) | ((unsigned)f2bf(ay * inv) << 16);
    *reinterpret_cast<unsigned*>(hcat + ((size_t)gw << 8) + lane * 2) = packed;
}

__global__ __launch_bounds__(256) void k_gemm(const ushort* hcat,
                                              const ushort* __restrict__ wb,
                                              const float* __restrict__ bias,
                                              float* out) {
    int t = threadIdx.x;
    int wid = t >> 6, lane = t & 63;
    int lr = lane & 15, lk = lane >> 4;
    int row0 = blockIdx.x * 128 + wid * 32;

    f32x4 acc[2][8];
    #pragma unroll
    for (int m = 0; m < 2; ++m)
        #pragma unroll
        for (int n = 0; n < 8; ++n) acc[m][n] = (f32x4)0.f;

    #pragma unroll
    for (int kb = 0; kb < 8; ++kb) {
        int kofs = kb * 32 + lk * 8;
        bf16x8 a[2];
        #pragma unroll
        for (int m = 0; m < 2; ++m) {
            int r = row0 + m * 16 + lr; if (r >= NN) r = NN - 1;
            a[m] = *reinterpret_cast<const bf16x8*>(hcat + ((size_t)r << 8) + kofs);
        }
        #pragma unroll
        for (int n = 0; n < 8; ++n) {
            bf16x8 bfr = *reinterpret_cast<const bf16x8*>(wb + (size_t)(n * 16 + lr) * K2 + kofs);
            acc[0][n] = __builtin_amdgcn_mfma_f32_16x16x32_bf16(a[0], bfr, acc[0][n], 0, 0, 0);
            acc[1][n] = __builtin_amdgcn_mfma_f32_16x16x32_bf16(a[1], bfr, acc[1][n], 0, 0, 0);
        }
    }

    float bv[8];
    #pragma unroll
    for (int n = 0; n < 8; ++n) bv[n] = bias[n * 16 + lr];

    #pragma unroll
    for (int m = 0; m < 2; ++m)
        #pragma unroll
        for (int j = 0; j < 4; ++j) {
            int r = row0 + m * 16 + lk * 4 + j;
            if (r < NN) {
                #pragma unroll
                for (int n = 0; n < 8; ++n)
                    out[(size_t)r * COUT + n * 16 + lr] = acc[m][n][j] + bv[n];
            }
        }
}

// ---------------- host ----------------

extern "C" void kernel_launch(void* const* d_in, const int* in_sizes, int n_in,
                              void* d_out, int out_size, void* d_ws, size_t ws_size,
                              hipStream_t stream) {
    (void)in_sizes; (void)n_in; (void)out_size;
    const float* x    = (const float*)d_in[0];
    const int*   esrc = (const int*)  d_in[1];
    const int*   edst = (const int*)  d_in[2];
    const float* wgt  = (const float*)d_in[3];
    const float* bias = (const float*)d_in[4];

    // ---- V3 workspace layout ----
    size_t ctr_ints  = 64 + NF;                           // 1632 ints (16B-mult)
    size_t bin1_recs = (size_t)NB1 * CAP1;                // 2,007,040 int2
    size_t bin2_recs = (size_t)NF * CAP2;                 // 2,408,448 int2
    size_t yh_elems  = (size_t)NN * CIN;                  // 12.8M ushort
    size_t need_v3 = ctr_ints * 4 + (bin1_recs + bin2_recs) * 8
                   + yh_elems * 2 + (size_t)K2 * COUT * 2 + 256;

    if (ws_size >= need_v3) {
        int*  wsi   = (int*)d_ws;
        int*  gctr1 = wsi;                                // [64]
        int*  gctr2 = wsi + 64;                           // [NF]
        int2* gbin1 = (int2*)(wsi + ctr_ints);
        int2* gbin2 = gbin1 + bin1_recs;
        ushort* yh  = (ushort*)(gbin2 + bin2_recs);
        ushort* wb  = yh + yh_elems;
        float* out  = (float*)d_out;

        hipMemsetAsync(wsi, 0, ctr_ints * sizeof(int), stream);
        k_castw<<<32, 256, 0, stream>>>(wgt, wb);
        k_p1   <<<1296, 256, 0, stream>>>(x, wb, bias, esrc, edst, gctr1, gbin1, yh, out);
        k_p2   <<<NB1 * 16, 256, 0, stream>>>(gctr1, gbin1, gctr2, gbin2);
        k_p3   <<<1563, 256, 0, stream>>>(gctr2, gbin2, yh, out);
    } else {
        // ---- round-5 fallback ----
        int* wsi  = (int*)d_ws;
        int* cnt  = wsi;
        int* csrF = wsi + NN;
        ushort* wb = (ushort*)(wsi + NN + (size_t)NN * CAP);
        ushort* hcat = (ushort*)d_out;

        hipMemsetAsync(cnt, 0, (size_t)NN * sizeof(int), stream);
        k_fuse2<<<NB_SCAT + NB_CAST + NB_CASTW, 256, 0, stream>>>(
            x, wgt, esrc, edst, cnt, csrF, hcat, wb);
        k_aggB <<<NN / 4, 256, 0, stream>>>(cnt, csrF, hcat);
        k_gemm <<<(NN + 127) / 128, 256, 0, stream>>>(hcat, wb, bias, (float*)d_out);
    }
}

// Round 7
// 174.459 us; speedup vs baseline: 7.6761x; 7.6761x over previous
//
#include <hip/hip_runtime.h>

#define NN   100000
#define NE   1600000
#define CIN  128
#define K2   256
#define COUT 128

typedef __attribute__((ext_vector_type(8))) short bf16x8;
typedef __attribute__((ext_vector_type(4))) float f32x4;

__device__ __forceinline__ ushort f2bf(float f) {
    union { float f; unsigned u; } v; v.f = f;
    unsigned r = (v.u + 0x7FFFu + ((v.u >> 16) & 1u)) >> 16;
    return (ushort)r;
}
__device__ __forceinline__ float bflo(unsigned p) {
    union { unsigned u; float f; } v; v.u = p << 16; return v.f;
}
__device__ __forceinline__ float bfhi(unsigned p) {
    union { unsigned u; float f; } v; v.u = p & 0xFFFF0000u; return v.f;
}

// ======================= V4: binned pipeline, sane consumer =======================

#define NB1      49        // coarse bins: dst>>11
#define CAP1     40960
#define NF       1568      // fine bins: dst>>6 (<=1562 used)
#define CAP2     1536
#define LCAP1    120
#define LCAP2    160
#define E1       3125      // NE / 512 bin-blocks

// ---- W f32 -> bf16 ----
__global__ __launch_bounds__(256) void k_castw(const float* __restrict__ w,
                                               ushort* __restrict__ wb) {
    int i = blockIdx.x * 256 + threadIdx.x;
    float4 v = *reinterpret_cast<const float4*>(w + (size_t)i * 4);
    ushort4 r; r.x = f2bf(v.x); r.y = f2bf(v.y); r.z = f2bf(v.z); r.w = f2bf(v.w);
    *reinterpret_cast<ushort4*>(wb + (size_t)i * 4) = r;
}

// ---- fused: dual GEMM (yh = x@Wh^T bf16, out = x@Wx^T + bias f32) || BIN1 ----
__global__ __launch_bounds__(256) void k_p1(const float* __restrict__ x,
                                            const ushort* __restrict__ wb,
                                            const float* __restrict__ bias,
                                            const int* __restrict__ esrc,
                                            const int* __restrict__ edst,
                                            int* __restrict__ gctr1,
                                            int2* __restrict__ gbin1,
                                            ushort* __restrict__ yh,
                                            float* __restrict__ out) {
    __shared__ int  lcnt[64];
    __shared__ int  lbase[64];
    __shared__ int2 lbuf[NB1 * LCAP1];    // 47 KB

    int b = blockIdx.x, t = threadIdx.x;
    bool isGemm; int rb;
    if (b < 1024) { isGemm = ((b & 1) == 0); rb = b >> 1; }
    else          { isGemm = true;           rb = 512 + (b - 1024); }

    if (isGemm) {
        int wid = t >> 6, lane = t & 63;
        int lr = lane & 15, lk = lane >> 4;
        int row0 = rb * 128 + wid * 32;
        #pragma unroll 1
        for (int pass = 0; pass < 2; ++pass) {
            int wko = pass * CIN;
            f32x4 acc[2][8];
            #pragma unroll
            for (int m = 0; m < 2; ++m)
                #pragma unroll
                for (int n = 0; n < 8; ++n) acc[m][n] = (f32x4)0.f;

            #pragma unroll
            for (int kb = 0; kb < 4; ++kb) {
                int kofs = kb * 32 + lk * 8;
                bf16x8 a[2];
                #pragma unroll
                for (int m = 0; m < 2; ++m) {
                    int r = row0 + m * 16 + lr; if (r >= NN) r = NN - 1;
                    const float* xp = x + (size_t)r * CIN + kofs;
                    float4 u0 = *reinterpret_cast<const float4*>(xp);
                    float4 u1 = *reinterpret_cast<const float4*>(xp + 4);
                    bf16x8 aa;
                    aa[0] = (short)f2bf(u0.x); aa[1] = (short)f2bf(u0.y);
                    aa[2] = (short)f2bf(u0.z); aa[3] = (short)f2bf(u0.w);
                    aa[4] = (short)f2bf(u1.x); aa[5] = (short)f2bf(u1.y);
                    aa[6] = (short)f2bf(u1.z); aa[7] = (short)f2bf(u1.w);
                    a[m] = aa;
                }
                #pragma unroll
                for (int n = 0; n < 8; ++n) {
                    bf16x8 bfr = *reinterpret_cast<const bf16x8*>(
                        wb + (size_t)(n * 16 + lr) * K2 + wko + kofs);
                    acc[0][n] = __builtin_amdgcn_mfma_f32_16x16x32_bf16(a[0], bfr, acc[0][n], 0, 0, 0);
                    acc[1][n] = __builtin_amdgcn_mfma_f32_16x16x32_bf16(a[1], bfr, acc[1][n], 0, 0, 0);
                }
            }
            if (pass == 0) {
                #pragma unroll
                for (int m = 0; m < 2; ++m)
                    #pragma unroll
                    for (int j = 0; j < 4; ++j) {
                        int r = row0 + m * 16 + lk * 4 + j;
                        if (r < NN) {
                            #pragma unroll
                            for (int n = 0; n < 8; ++n)
                                yh[(size_t)r * CIN + n * 16 + lr] = f2bf(acc[m][n][j]);
                        }
                    }
            } else {
                float bv[8];
                #pragma unroll
                for (int n = 0; n < 8; ++n) bv[n] = bias[n * 16 + lr];
                #pragma unroll
                for (int m = 0; m < 2; ++m)
                    #pragma unroll
                    for (int j = 0; j < 4; ++j) {
                        int r = row0 + m * 16 + lk * 4 + j;
                        if (r < NN) {
                            #pragma unroll
                            for (int n = 0; n < 8; ++n)
                                out[(size_t)r * COUT + n * 16 + lr] = acc[m][n][j] + bv[n];
                        }
                    }
            }
        }
    } else {
        int base = rb * E1;
        for (int i = t; i < 64; i += 256) lcnt[i] = 0;
        __syncthreads();
        for (int e = t; e < E1; e += 256) {
            int d = edst[base + e], s = esrc[base + e];
            int c = d >> 11;
            int p = atomicAdd(&lcnt[c], 1);
            if (p < LCAP1) lbuf[c * LCAP1 + p] = make_int2(d, s);
            else {
                int gp = atomicAdd(&gctr1[c], 1);
                if (gp < CAP1) gbin1[(size_t)c * CAP1 + gp] = make_int2(d, s);
            }
        }
        __syncthreads();
        if (t < NB1) {
            int n = lcnt[t]; if (n > LCAP1) n = LCAP1;
            lbase[t] = atomicAdd(&gctr1[t], n);
            lcnt[t] = n;
        }
        __syncthreads();
        for (int c = 0; c < NB1; ++c) {
            int n = lcnt[c], g0 = lbase[c];
            for (int i = t; i < n; i += 256)
                if (g0 + i < CAP1)
                    gbin1[(size_t)c * CAP1 + g0 + i] = lbuf[c * LCAP1 + i];
        }
    }
}

// ---- BIN2: coarse -> fine (64-node) bins ----
__global__ __launch_bounds__(256) void k_p2(const int* __restrict__ gctr1,
                                            const int2* __restrict__ gbin1,
                                            int* __restrict__ gctr2,
                                            int2* __restrict__ gbin2) {
    __shared__ int  lcnt[32];
    __shared__ int  lbase[32];
    __shared__ int2 lbuf[32 * LCAP2];     // 40 KB
    int c = blockIdx.x >> 4;
    int j = blockIdx.x & 15;
    int t = threadIdx.x;
    int cnt = gctr1[c]; if (cnt > CAP1) cnt = CAP1;
    int share = (cnt + 15) >> 4;
    int lo = j * share, hi = min(cnt, lo + share);
    if (t < 32) lcnt[t] = 0;
    __syncthreads();
    for (int i = lo + t; i < hi; i += 256) {
        int2 r = gbin1[(size_t)c * CAP1 + i];
        int fl = (r.x >> 6) & 31;
        int p = atomicAdd(&lcnt[fl], 1);
        if (p < LCAP2) lbuf[fl * LCAP2 + p] = r;
        else {
            int f = (c << 5) + fl;
            int gp = atomicAdd(&gctr2[f], 1);
            if (gp < CAP2) gbin2[(size_t)f * CAP2 + gp] = r;
        }
    }
    __syncthreads();
    if (t < 32) {
        int n = lcnt[t]; if (n > LCAP2) n = LCAP2;
        lbase[t] = atomicAdd(&gctr2[(c << 5) + t], n);
        lcnt[t] = n;
    }
    __syncthreads();
    for (int fl = 0; fl < 32; ++fl) {
        int n = lcnt[fl], g0 = lbase[fl];
        size_t fb = (size_t)((c << 5) + fl) * CAP2;
        for (int i = t; i < n; i += 256)
            if (g0 + i < CAP2) gbin2[fb + g0 + i] = lbuf[fl * LCAP2 + i];
    }
}

// ---- NEW p3: LDS counting-sort, then register-accumulate gather + coalesced RMW ----
__global__ __launch_bounds__(256) void k_p3(const int* __restrict__ gctr2,
                                            const int2* __restrict__ gbin2,
                                            const ushort* __restrict__ yh,
                                            float* __restrict__ out) {
    __shared__ int2 lrec[CAP2];           // 12 KB
    __shared__ int  ssrc[CAP2];           // 6 KB
    __shared__ int  hcnt[64];
    __shared__ int  hbase[64];
    __shared__ int  hcur[64];
    int f = blockIdx.x, t = threadIdx.x;
    int wid = t >> 6, lane = t & 63;

    if (t < 64) hcnt[t] = 0;
    __syncthreads();

    int m = gctr2[f]; if (m > CAP2) m = CAP2;

    // A: stage records + histogram over 64 local nodes
    for (int i = t; i < m; i += 256) {
        int2 r = gbin2[(size_t)f * CAP2 + i];
        lrec[i] = r;
        atomicAdd(&hcnt[r.x & 63], 1);
    }
    __syncthreads();

    // B: exclusive prefix over 64 counters (wave 0, shfl scan)
    if (t < 64) {
        int v = hcnt[t];
        int s = v;
        #pragma unroll
        for (int d = 1; d < 64; d <<= 1) {
            int u = __shfl_up(s, d);
            if (lane >= d) s += u;
        }
        hbase[t] = s - v;
        hcur[t]  = s - v;
    }
    __syncthreads();

    // C: scatter srcs into per-node contiguous lists
    for (int i = t; i < m; i += 256) {
        int2 r = lrec[i];
        int p = atomicAdd(&hcur[r.x & 63], 1);
        ssrc[p] = r.y;
    }
    __syncthreads();

    // D/E: each wave handles 16 nodes; lanes = channel pairs
    int node0 = f << 6;
    for (int i = wid * 16; i < wid * 16 + 16; ++i) {
        int n = node0 + i;
        if (n >= NN) break;
        int d0 = hbase[i], dg = hcnt[i];
        float ax = 0.f, ay = 0.f;
        int e = 0;
        for (; e + 7 < dg; e += 8) {
            int s0 = ssrc[d0+e],   s1 = ssrc[d0+e+1], s2 = ssrc[d0+e+2], s3 = ssrc[d0+e+3];
            int s4 = ssrc[d0+e+4], s5 = ssrc[d0+e+5], s6 = ssrc[d0+e+6], s7 = ssrc[d0+e+7];
            unsigned v0 = *reinterpret_cast<const unsigned*>(yh + ((size_t)s0 << 7) + lane * 2);
            unsigned v1 = *reinterpret_cast<const unsigned*>(yh + ((size_t)s1 << 7) + lane * 2);
            unsigned v2 = *reinterpret_cast<const unsigned*>(yh + ((size_t)s2 << 7) + lane * 2);
            unsigned v3 = *reinterpret_cast<const unsigned*>(yh + ((size_t)s3 << 7) + lane * 2);
            unsigned v4 = *reinterpret_cast<const unsigned*>(yh + ((size_t)s4 << 7) + lane * 2);
            unsigned v5 = *reinterpret_cast<const unsigned*>(yh + ((size_t)s5 << 7) + lane * 2);
            unsigned v6 = *reinterpret_cast<const unsigned*>(yh + ((size_t)s6 << 7) + lane * 2);
            unsigned v7 = *reinterpret_cast<const unsigned*>(yh + ((size_t)s7 << 7) + lane * 2);
            ax += bflo(v0) + bflo(v1) + bflo(v2) + bflo(v3)
                + bflo(v4) + bflo(v5) + bflo(v6) + bflo(v7);
            ay += bfhi(v0) + bfhi(v1) + bfhi(v2) + bfhi(v3)
                + bfhi(v4) + bfhi(v5) + bfhi(v6) + bfhi(v7);
        }
        for (; e < dg; ++e) {
            int s = ssrc[d0 + e];
            unsigned v = *reinterpret_cast<const unsigned*>(yh + ((size_t)s << 7) + lane * 2);
            ax += bflo(v); ay += bfhi(v);
        }
        float inv = (dg > 0) ? 1.0f / (float)dg : 0.0f;
        float2* po = reinterpret_cast<float2*>(out + ((size_t)n << 7) + lane * 2);
        float2 o = *po;
        o.x += ax * inv; o.y += ay * inv;
        *po = o;
    }
}

// ======================= V2 fallback (round-5, validated) =======================

#define NXCD  8
#define PART  ((NN + NXCD - 1) / NXCD)
#define NB_SCAT  2048
#define NB_CAST  12500
#define NB_CASTW 32
#define CAP  64

__global__ __launch_bounds__(256) void k_fuse2(const float* __restrict__ x,
                                               const float* __restrict__ w,
                                               const int* __restrict__ src,
                                               const int* __restrict__ dst,
                                               int* __restrict__ cnt,
                                               int* __restrict__ csrF,
                                               ushort* hcat,
                                               ushort* __restrict__ wb) {
    int b = blockIdx.x, t = threadIdx.x;
    if (b < NB_SCAT) {
        int part = b & (NXCD - 1);
        int slot = b >> 3;
        int lo = part * PART;
        int hi = lo + PART; if (hi > NN) hi = NN;
        const int NCH = NE / 4;
        for (int c = slot * 256 + t; c < NCH; c += 256 * 256) {
            int4 d = *reinterpret_cast<const int4*>(dst + (size_t)c * 4);
            int4 s = *reinterpret_cast<const int4*>(src + (size_t)c * 4);
            if (d.x >= lo && d.x < hi) { int p = atomicAdd(&cnt[d.x], 1); csrF[(d.x << 6) + p] = s.x; }
            if (d.y >= lo && d.y < hi) { int p = atomicAdd(&cnt[d.y], 1); csrF[(d.y << 6) + p] = s.y; }
            if (d.z >= lo && d.z < hi) { int p = atomicAdd(&cnt[d.z], 1); csrF[(d.z << 6) + p] = s.z; }
            if (d.w >= lo && d.w < hi) { int p = atomicAdd(&cnt[d.w], 1); csrF[(d.w << 6) + p] = s.w; }
        }
    } else if (b < NB_SCAT + NB_CAST) {
        int i = (b - NB_SCAT) * 256 + t;
        int node = i >> 5, c4 = (i & 31) * 4;
        float4 v = *reinterpret_cast<const float4*>(x + (size_t)node * CIN + c4);
        ushort4 r; r.x = f2bf(v.x); r.y = f2bf(v.y); r.z = f2bf(v.z); r.w = f2bf(v.w);
        *reinterpret_cast<ushort4*>(hcat + (size_t)node * K2 + CIN + c4) = r;
    } else {
        int i = (b - NB_SCAT - NB_CAST) * 256 + t;
        float4 v = *reinterpret_cast<const float4*>(w + (size_t)i * 4);
        ushort4 r; r.x = f2bf(v.x); r.y = f2bf(v.y); r.z = f2bf(v.z); r.w = f2bf(v.w);
        *reinterpret_cast<ushort4*>(wb + (size_t)i * 4) = r;
    }
}

__global__ __launch_bounds__(256) void k_aggB(const int* __restrict__ cnt,
                                              const int* __restrict__ csrF,
                                              ushort* hcat) {
    int gw   = (blockIdx.x * 256 + threadIdx.x) >> 6;
    int lane = threadIdx.x & 63;
    if (gw >= NN) return;
    int gws = __builtin_amdgcn_readfirstlane(gw);
    int deg = cnt[gws];
    const int4* b4 = reinterpret_cast<const int4*>(csrF + ((size_t)gws << 6));
    int boff = CIN + lane * 2;
    float ax = 0.f, ay = 0.f;
    for (int e = 0; e < deg; e += 8) {
        int4 c0 = b4[(e >> 2)];
        int4 c1 = b4[(e >> 2) + 1];
        int ss[8] = {c0.x, c0.y, c0.z, c0.w, c1.x, c1.y, c1.z, c1.w};
        #pragma unroll
        for (int k = 0; k < 8; ++k) {
            bool ok = (e + k) < deg;
            int s = ok ? ss[k] : 0;
            unsigned v = *reinterpret_cast<const unsigned*>(hcat + ((size_t)s << 8) + boff);
            float mq = ok ? 1.f : 0.f;
            ax += mq * bflo(v); ay += mq * bfhi(v);
        }
    }
    float inv = (deg > 0) ? 1.0f / (float)deg : 0.0f;
    unsigned packed = (unsigned)f2bf(ax * inv) | ((unsigned)f2bf(ay * inv) << 16);
    *reinterpret_cast<unsigned*>(hcat + ((size_t)gw << 8) + lane * 2) = packed;
}

__global__ __launch_bounds__(256) void k_gemm(const ushort* hcat,
                                              const ushort* __restrict__ wb,
                                              const float* __restrict__ bias,
                                              float* out) {
    int t = threadIdx.x;
    int wid = t >> 6, lane = t & 63;
    int lr = lane & 15, lk = lane >> 4;
    int row0 = blockIdx.x * 128 + wid * 32;

    f32x4 acc[2][8];
    #pragma unroll
    for (int m = 0; m < 2; ++m)
        #pragma unroll
        for (int n = 0; n < 8; ++n) acc[m][n] = (f32x4)0.f;

    #pragma unroll
    for (int kb = 0; kb < 8; ++kb) {
        int kofs = kb * 32 + lk * 8;
        bf16x8 a[2];
        #pragma unroll
        for (int m = 0; m < 2; ++m) {
            int r = row0 + m * 16 + lr; if (r >= NN) r = NN - 1;
            a[m] = *reinterpret_cast<const bf16x8*>(hcat + ((size_t)r << 8) + kofs);
        }
        #pragma unroll
        for (int n = 0; n < 8; ++n) {
            bf16x8 bfr = *reinterpret_cast<const bf16x8*>(wb + (size_t)(n * 16 + lr) * K2 + kofs);
            acc[0][n] = __builtin_amdgcn_mfma_f32_16x16x32_bf16(a[0], bfr, acc[0][n], 0, 0, 0);
            acc[1][n] = __builtin_amdgcn_mfma_f32_16x16x32_bf16(a[1], bfr, acc[1][n], 0, 0, 0);
        }
    }

    float bv[8];
    #pragma unroll
    for (int n = 0; n < 8; ++n) bv[n] = bias[n * 16 + lr];

    #pragma unroll
    for (int m = 0; m < 2; ++m)
        #pragma unroll
        for (int j = 0; j < 4; ++j) {
            int r = row0 + m * 16 + lk * 4 + j;
            if (r < NN) {
                #pragma unroll
                for (int n = 0; n < 8; ++n)
                    out[(size_t)r * COUT + n * 16 + lr] = acc[m][n][j] + bv[n];
            }
        }
}

// ---------------- host ----------------

extern "C" void kernel_launch(void* const* d_in, const int* in_sizes, int n_in,
                              void* d_out, int out_size, void* d_ws, size_t ws_size,
                              hipStream_t stream) {
    (void)in_sizes; (void)n_in; (void)out_size;
    const float* x    = (const float*)d_in[0];
    const int*   esrc = (const int*)  d_in[1];
    const int*   edst = (const int*)  d_in[2];
    const float* wgt  = (const float*)d_in[3];
    const float* bias = (const float*)d_in[4];

    size_t ctr_ints  = 64 + NF;
    size_t bin1_recs = (size_t)NB1 * CAP1;
    size_t bin2_recs = (size_t)NF * CAP2;
    size_t yh_elems  = (size_t)NN * CIN;
    size_t need_v4 = ctr_ints * 4 + (bin1_recs + bin2_recs) * 8
                   + yh_elems * 2 + (size_t)K2 * COUT * 2 + 256;

    if (ws_size >= need_v4) {
        int*  wsi   = (int*)d_ws;
        int*  gctr1 = wsi;                                // [64]
        int*  gctr2 = wsi + 64;                           // [NF]
        int2* gbin1 = (int2*)(wsi + ctr_ints);
        int2* gbin2 = gbin1 + bin1_recs;
        ushort* yh  = (ushort*)(gbin2 + bin2_recs);
        ushort* wb  = yh + yh_elems;
        float* out  = (float*)d_out;

        hipMemsetAsync(wsi, 0, ctr_ints * sizeof(int), stream);
        k_castw<<<32, 256, 0, stream>>>(wgt, wb);
        k_p1   <<<1296, 256, 0, stream>>>(x, wb, bias, esrc, edst, gctr1, gbin1, yh, out);
        k_p2   <<<NB1 * 16, 256, 0, stream>>>(gctr1, gbin1, gctr2, gbin2);
        k_p3   <<<1563, 256, 0, stream>>>(gctr2, gbin2, yh, out);
    } else {
        int* wsi  = (int*)d_ws;
        int* cnt  = wsi;
        int* csrF = wsi + NN;
        ushort* wb = (ushort*)(wsi + NN + (size_t)NN * CAP);
        ushort* hcat = (ushort*)d_out;

        hipMemsetAsync(cnt, 0, (size_t)NN * sizeof(int), stream);
        k_fuse2<<<NB_SCAT + NB_CAST + NB_CASTW, 256, 0, stream>>>(
            x, wgt, esrc, edst, cnt, csrF, hcat, wb);
        k_aggB <<<NN / 4, 256, 0, stream>>>(cnt, csrF, hcat);
        k_gemm <<<(NN + 127) / 128, 256, 0, stream>>>(hcat, wb, bias, (float*)d_out);
    }
}

// Round 9
// 170.301 us; speedup vs baseline: 7.8635x; 1.0244x over previous
//
#include <hip/hip_runtime.h>

#define NN   100000
#define NE   1600000
#define CIN  128
#define K2   256
#define COUT 128

typedef __attribute__((ext_vector_type(8))) short bf16x8;
typedef __attribute__((ext_vector_type(4))) float f32x4;

__device__ __forceinline__ ushort f2bf(float f) {
    union { float f; unsigned u; } v; v.f = f;
    unsigned r = (v.u + 0x7FFFu + ((v.u >> 16) & 1u)) >> 16;
    return (ushort)r;
}
__device__ __forceinline__ float bflo(unsigned p) {
    union { unsigned u; float f; } v; v.u = p << 16; return v.f;
}
__device__ __forceinline__ float bfhi(unsigned p) {
    union { unsigned u; float f; } v; v.u = p & 0xFFFF0000u; return v.f;
}

// ======================= V5: binned pipeline, 4B records =======================
// rec = src (bits 0..16) | (dst & 2047) << 17
//   bin1 index: dst>>11 (implicit by bin)  |  p2 key: (rec>>23)&31  |  p3 node: (rec>>17)&63

#define NB1      49        // coarse bins: dst>>11
#define CAP1     40960
#define NF       1568      // fine bins: dst>>6 (<=1562 used)
#define CAP2     1536
#define LCAP1    120
#define LCAP2    160
#define E1       3125      // NE / 512 bin-blocks
#define SRCMASK  0x1FFFF

// ---- W f32 -> bf16 ----
__global__ __launch_bounds__(256) void k_castw(const float* __restrict__ w,
                                               ushort* __restrict__ wb) {
    int i = blockIdx.x * 256 + threadIdx.x;
    float4 v = *reinterpret_cast<const float4*>(w + (size_t)i * 4);
    ushort4 r; r.x = f2bf(v.x); r.y = f2bf(v.y); r.z = f2bf(v.z); r.w = f2bf(v.w);
    *reinterpret_cast<ushort4*>(wb + (size_t)i * 4) = r;
}

// ---- fused: dual GEMM (yh = x@Wh^T bf16, out = x@Wx^T + bias f32) || BIN1 ----
__global__ __launch_bounds__(256) void k_p1(const float* __restrict__ x,
                                            const ushort* __restrict__ wb,
                                            const float* __restrict__ bias,
                                            const int* __restrict__ esrc,
                                            const int* __restrict__ edst,
                                            int* __restrict__ gctr1,
                                            unsigned* __restrict__ gbin1,
                                            ushort* __restrict__ yh,
                                            float* __restrict__ out) {
    __shared__ int      lcnt[64];
    __shared__ int      lbase[64];
    __shared__ unsigned lbuf[NB1 * LCAP1];    // 23.5 KB

    int b = blockIdx.x, t = threadIdx.x;
    bool isGemm; int rb;
    if (b < 1024) { isGemm = ((b & 1) == 0); rb = b >> 1; }
    else          { isGemm = true;           rb = 512 + (b - 1024); }

    if (isGemm) {
        int wid = t >> 6, lane = t & 63;
        int lr = lane & 15, lk = lane >> 4;
        int row0 = rb * 128 + wid * 32;
        #pragma unroll 1
        for (int pass = 0; pass < 2; ++pass) {
            int wko = pass * CIN;
            f32x4 acc[2][8];
            #pragma unroll
            for (int m = 0; m < 2; ++m)
                #pragma unroll
                for (int n = 0; n < 8; ++n) acc[m][n] = (f32x4)0.f;

            #pragma unroll
            for (int kb = 0; kb < 4; ++kb) {
                int kofs = kb * 32 + lk * 8;
                bf16x8 a[2];
                #pragma unroll
                for (int m = 0; m < 2; ++m) {
                    int r = row0 + m * 16 + lr; if (r >= NN) r = NN - 1;
                    const float* xp = x + (size_t)r * CIN + kofs;
                    float4 u0 = *reinterpret_cast<const float4*>(xp);
                    float4 u1 = *reinterpret_cast<const float4*>(xp + 4);
                    bf16x8 aa;
                    aa[0] = (short)f2bf(u0.x); aa[1] = (short)f2bf(u0.y);
                    aa[2] = (short)f2bf(u0.z); aa[3] = (short)f2bf(u0.w);
                    aa[4] = (short)f2bf(u1.x); aa[5] = (short)f2bf(u1.y);
                    aa[6] = (short)f2bf(u1.z); aa[7] = (short)f2bf(u1.w);
                    a[m] = aa;
                }
                #pragma unroll
                for (int n = 0; n < 8; ++n) {
                    bf16x8 bfr = *reinterpret_cast<const bf16x8*>(
                        wb + (size_t)(n * 16 + lr) * K2 + wko + kofs);
                    acc[0][n] = __builtin_amdgcn_mfma_f32_16x16x32_bf16(a[0], bfr, acc[0][n], 0, 0, 0);
                    acc[1][n] = __builtin_amdgcn_mfma_f32_16x16x32_bf16(a[1], bfr, acc[1][n], 0, 0, 0);
                }
            }
            if (pass == 0) {
                #pragma unroll
                for (int m = 0; m < 2; ++m)
                    #pragma unroll
                    for (int j = 0; j < 4; ++j) {
                        int r = row0 + m * 16 + lk * 4 + j;
                        if (r < NN) {
                            #pragma unroll
                            for (int n = 0; n < 8; ++n)
                                yh[(size_t)r * CIN + n * 16 + lr] = f2bf(acc[m][n][j]);
                        }
                    }
            } else {
                float bv[8];
                #pragma unroll
                for (int n = 0; n < 8; ++n) bv[n] = bias[n * 16 + lr];
                #pragma unroll
                for (int m = 0; m < 2; ++m)
                    #pragma unroll
                    for (int j = 0; j < 4; ++j) {
                        int r = row0 + m * 16 + lk * 4 + j;
                        if (r < NN) {
                            #pragma unroll
                            for (int n = 0; n < 8; ++n)
                                out[(size_t)r * COUT + n * 16 + lr] = acc[m][n][j] + bv[n];
                        }
                    }
            }
        }
    } else {
        int base = rb * E1;
        for (int i = t; i < 64; i += 256) lcnt[i] = 0;
        __syncthreads();
        for (int e = t; e < E1; e += 256) {
            int d = edst[base + e], s = esrc[base + e];
            int c = d >> 11;
            unsigned rec = (unsigned)s | ((unsigned)(d & 2047) << 17);
            int p = atomicAdd(&lcnt[c], 1);
            if (p < LCAP1) lbuf[c * LCAP1 + p] = rec;
            else {
                int gp = atomicAdd(&gctr1[c], 1);
                if (gp < CAP1) gbin1[(size_t)c * CAP1 + gp] = rec;
            }
        }
        __syncthreads();
        if (t < NB1) {
            int n = lcnt[t]; if (n > LCAP1) n = LCAP1;
            lbase[t] = atomicAdd(&gctr1[t], n);
            lcnt[t] = n;
        }
        __syncthreads();
        for (int c = 0; c < NB1; ++c) {
            int n = lcnt[c], g0 = lbase[c];
            for (int i = t; i < n; i += 256)
                if (g0 + i < CAP1)
                    gbin1[(size_t)c * CAP1 + g0 + i] = lbuf[c * LCAP1 + i];
        }
    }
}

// ---- BIN2: coarse -> fine (64-node) bins ----
__global__ __launch_bounds__(256) void k_p2(const int* __restrict__ gctr1,
                                            const unsigned* __restrict__ gbin1,
                                            int* __restrict__ gctr2,
                                            unsigned* __restrict__ gbin2) {
    __shared__ int      lcnt[32];
    __shared__ int      lbase[32];
    __shared__ unsigned lbuf[32 * LCAP2];     // 20 KB
    int c = blockIdx.x >> 4;
    int j = blockIdx.x & 15;
    int t = threadIdx.x;
    int cnt = gctr1[c]; if (cnt > CAP1) cnt = CAP1;
    int share = (cnt + 15) >> 4;
    int lo = j * share, hi = min(cnt, lo + share);
    if (t < 32) lcnt[t] = 0;
    __syncthreads();
    for (int i = lo + t; i < hi; i += 256) {
        unsigned r = gbin1[(size_t)c * CAP1 + i];
        int fl = (r >> 23) & 31;
        int p = atomicAdd(&lcnt[fl], 1);
        if (p < LCAP2) lbuf[fl * LCAP2 + p] = r;
        else {
            int f = (c << 5) + fl;
            int gp = atomicAdd(&gctr2[f], 1);
            if (gp < CAP2) gbin2[(size_t)f * CAP2 + gp] = r;
        }
    }
    __syncthreads();
    if (t < 32) {
        int n = lcnt[t]; if (n > LCAP2) n = LCAP2;
        lbase[t] = atomicAdd(&gctr2[(c << 5) + t], n);
        lcnt[t] = n;
    }
    __syncthreads();
    for (int fl = 0; fl < 32; ++fl) {
        int n = lcnt[fl], g0 = lbase[fl];
        size_t fb = (size_t)((c << 5) + fl) * CAP2;
        for (int i = t; i < n; i += 256)
            if (g0 + i < CAP2) gbin2[fb + g0 + i] = lbuf[fl * LCAP2 + i];
    }
}

// ---- p3: LDS counting-sort, paired gather (2 edges/wave-instr), f32x4 NT RMW ----
__global__ __launch_bounds__(256) void k_p3(const int* __restrict__ gctr2,
                                            const unsigned* __restrict__ gbin2,
                                            const ushort* __restrict__ yh,
                                            float* __restrict__ out) {
    __shared__ unsigned lrec[CAP2];           // 6 KB
    __shared__ int      ssrc[CAP2];           // 6 KB
    __shared__ int      hcnt[64];
    __shared__ int      hbase[64];
    __shared__ int      hcur[64];
    int f = blockIdx.x, t = threadIdx.x;
    int wid = t >> 6, lane = t & 63;

    if (t < 64) hcnt[t] = 0;
    __syncthreads();

    int m = gctr2[f]; if (m > CAP2) m = CAP2;

    // A: stage records + histogram over 64 local nodes
    for (int i = t; i < m; i += 256) {
        unsigned r = gbin2[(size_t)f * CAP2 + i];
        lrec[i] = r;
        atomicAdd(&hcnt[(r >> 17) & 63], 1);
    }
    __syncthreads();

    // B: exclusive prefix over 64 counters (wave 0)
    if (t < 64) {
        int v = hcnt[t];
        int s = v;
        #pragma unroll
        for (int d = 1; d < 64; d <<= 1) {
            int u = __shfl_up(s, d);
            if (lane >= d) s += u;
        }
        hbase[t] = s - v;
        hcur[t]  = s - v;
    }
    __syncthreads();

    // C: scatter srcs into per-node contiguous lists
    for (int i = t; i < m; i += 256) {
        unsigned r = lrec[i];
        int p = atomicAdd(&hcur[(r >> 17) & 63], 1);
        ssrc[p] = (int)(r & SRCMASK);
    }
    __syncthreads();

    // D: each wave handles 16 nodes; halves of the wave process 2 edges at once
    int node0 = f << 6;
    int half = lane >> 5;
    int chof = (lane & 31) * 4;               // ushort offset: 4 channels per lane
    for (int i = wid * 16; i < wid * 16 + 16; ++i) {
        int n = node0 + i;
        if (n >= NN) break;
        int d0 = hbase[i], dg = hcnt[i];
        float a0 = 0.f, a1 = 0.f, a2 = 0.f, a3 = 0.f;
        for (int e = 0; e < dg; e += 8) {
            #pragma unroll
            for (int q = 0; q < 4; ++q) {
                int idx = e + q * 2 + half;
                uint2 v = make_uint2(0u, 0u);
                if (idx < dg) {
                    int s = ssrc[d0 + idx];
                    v = *reinterpret_cast<const uint2*>(yh + ((size_t)s << 7) + chof);
                }
                a0 += bflo(v.x); a1 += bfhi(v.x);
                a2 += bflo(v.y); a3 += bfhi(v.y);
            }
        }
        // combine wave halves (both halves hold the same 4 channels)
        a0 += __shfl(a0, lane ^ 32);
        a1 += __shfl(a1, lane ^ 32);
        a2 += __shfl(a2, lane ^ 32);
        a3 += __shfl(a3, lane ^ 32);
        float inv = (dg > 0) ? 1.0f / (float)dg : 0.0f;
        if (lane < 32) {
            f32x4* po = reinterpret_cast<f32x4*>(out + ((size_t)n << 7) + chof);
            f32x4 o = __builtin_nontemporal_load(po);
            o[0] += a0 * inv; o[1] += a1 * inv;
            o[2] += a2 * inv; o[3] += a3 * inv;
            __builtin_nontemporal_store(o, po);
        }
    }
}

// ======================= V2 fallback (round-5, validated) =======================

#define NXCD  8
#define PART  ((NN + NXCD - 1) / NXCD)
#define NB_SCAT  2048
#define NB_CAST  12500
#define NB_CASTW 32
#define CAP  64

__global__ __launch_bounds__(256) void k_fuse2(const float* __restrict__ x,
                                               const float* __restrict__ w,
                                               const int* __restrict__ src,
                                               const int* __restrict__ dst,
                                               int* __restrict__ cnt,
                                               int* __restrict__ csrF,
                                               ushort* hcat,
                                               ushort* __restrict__ wb) {
    int b = blockIdx.x, t = threadIdx.x;
    if (b < NB_SCAT) {
        int part = b & (NXCD - 1);
        int slot = b >> 3;
        int lo = part * PART;
        int hi = lo + PART; if (hi > NN) hi = NN;
        const int NCH = NE / 4;
        for (int c = slot * 256 + t; c < NCH; c += 256 * 256) {
            int4 d = *reinterpret_cast<const int4*>(dst + (size_t)c * 4);
            int4 s = *reinterpret_cast<const int4*>(src + (size_t)c * 4);
            if (d.x >= lo && d.x < hi) { int p = atomicAdd(&cnt[d.x], 1); csrF[(d.x << 6) + p] = s.x; }
            if (d.y >= lo && d.y < hi) { int p = atomicAdd(&cnt[d.y], 1); csrF[(d.y << 6) + p] = s.y; }
            if (d.z >= lo && d.z < hi) { int p = atomicAdd(&cnt[d.z], 1); csrF[(d.z << 6) + p] = s.z; }
            if (d.w >= lo && d.w < hi) { int p = atomicAdd(&cnt[d.w], 1); csrF[(d.w << 6) + p] = s.w; }
        }
    } else if (b < NB_SCAT + NB_CAST) {
        int i = (b - NB_SCAT) * 256 + t;
        int node = i >> 5, c4 = (i & 31) * 4;
        float4 v = *reinterpret_cast<const float4*>(x + (size_t)node * CIN + c4);
        ushort4 r; r.x = f2bf(v.x); r.y = f2bf(v.y); r.z = f2bf(v.z); r.w = f2bf(v.w);
        *reinterpret_cast<ushort4*>(hcat + (size_t)node * K2 + CIN + c4) = r;
    } else {
        int i = (b - NB_SCAT - NB_CAST) * 256 + t;
        float4 v = *reinterpret_cast<const float4*>(w + (size_t)i * 4);
        ushort4 r; r.x = f2bf(v.x); r.y = f2bf(v.y); r.z = f2bf(v.z); r.w = f2bf(v.w);
        *reinterpret_cast<ushort4*>(wb + (size_t)i * 4) = r;
    }
}

__global__ __launch_bounds__(256) void k_aggB(const int* __restrict__ cnt,
                                              const int* __restrict__ csrF,
                                              ushort* hcat) {
    int gw   = (blockIdx.x * 256 + threadIdx.x) >> 6;
    int lane = threadIdx.x & 63;
    if (gw >= NN) return;
    int gws = __builtin_amdgcn_readfirstlane(gw);
    int deg = cnt[gws];
    const int4* b4 = reinterpret_cast<const int4*>(csrF + ((size_t)gws << 6));
    int boff = CIN + lane * 2;
    float ax = 0.f, ay = 0.f;
    for (int e = 0; e < deg; e += 8) {
        int4 c0 = b4[(e >> 2)];
        int4 c1 = b4[(e >> 2) + 1];
        int ss[8] = {c0.x, c0.y, c0.z, c0.w, c1.x, c1.y, c1.z, c1.w};
        #pragma unroll
        for (int k = 0; k < 8; ++k) {
            bool ok = (e + k) < deg;
            int s = ok ? ss[k] : 0;
            unsigned v = *reinterpret_cast<const unsigned*>(hcat + ((size_t)s << 8) + boff);
            float mq = ok ? 1.f : 0.f;
            ax += mq * bflo(v); ay += mq * bfhi(v);
        }
    }
    float inv = (deg > 0) ? 1.0f / (float)deg : 0.0f;
    unsigned packed = (unsigned)f2bf(ax * inv) | ((unsigned)f2bf(ay * inv) << 16);
    *reinterpret_cast<unsigned*>(hcat + ((size_t)gw << 8) + lane * 2) = packed;
}

__global__ __launch_bounds__(256) void k_gemm(const ushort* hcat,
                                              const ushort* __restrict__ wb,
                                              const float* __restrict__ bias,
                                              float* out) {
    int t = threadIdx.x;
    int wid = t >> 6, lane = t & 63;
    int lr = lane & 15, lk = lane >> 4;
    int row0 = blockIdx.x * 128 + wid * 32;

    f32x4 acc[2][8];
    #pragma unroll
    for (int m = 0; m < 2; ++m)
        #pragma unroll
        for (int n = 0; n < 8; ++n) acc[m][n] = (f32x4)0.f;

    #pragma unroll
    for (int kb = 0; kb < 8; ++kb) {
        int kofs = kb * 32 + lk * 8;
        bf16x8 a[2];
        #pragma unroll
        for (int m = 0; m < 2; ++m) {
            int r = row0 + m * 16 + lr; if (r >= NN) r = NN - 1;
            a[m] = *reinterpret_cast<const bf16x8*>(hcat + ((size_t)r << 8) + kofs);
        }
        #pragma unroll
        for (int n = 0; n < 8; ++n) {
            bf16x8 bfr = *reinterpret_cast<const bf16x8*>(wb + (size_t)(n * 16 + lr) * K2 + kofs);
            acc[0][n] = __builtin_amdgcn_mfma_f32_16x16x32_bf16(a[0], bfr, acc[0][n], 0, 0, 0);
            acc[1][n] = __builtin_amdgcn_mfma_f32_16x16x32_bf16(a[1], bfr, acc[1][n], 0, 0, 0);
        }
    }

    float bv[8];
    #pragma unroll
    for (int n = 0; n < 8; ++n) bv[n] = bias[n * 16 + lr];

    #pragma unroll
    for (int m = 0; m < 2; ++m)
        #pragma unroll
        for (int j = 0; j < 4; ++j) {
            int r = row0 + m * 16 + lk * 4 + j;
            if (r < NN) {
                #pragma unroll
                for (int n = 0; n < 8; ++n)
                    out[(size_t)r * COUT + n * 16 + lr] = acc[m][n][j] + bv[n];
            }
        }
}

// ---------------- host ----------------

extern "C" void kernel_launch(void* const* d_in, const int* in_sizes, int n_in,
                              void* d_out, int out_size, void* d_ws, size_t ws_size,
                              hipStream_t stream) {
    (void)in_sizes; (void)n_in; (void)out_size;
    const float* x    = (const float*)d_in[0];
    const int*   esrc = (const int*)  d_in[1];
    const int*   edst = (const int*)  d_in[2];
    const float* wgt  = (const float*)d_in[3];
    const float* bias = (const float*)d_in[4];

    size_t ctr_ints  = 64 + NF;                          // 1632
    size_t bin1_recs = (size_t)NB1 * CAP1;               // 2,007,040 u32
    size_t bin2_recs = (size_t)NF * CAP2;                // 2,408,448 u32
    size_t yh_elems  = (size_t)NN * CIN;                 // 12.8M ushort
    size_t need_v5 = ctr_ints * 4 + (bin1_recs + bin2_recs) * 4
                   + yh_elems * 2 + (size_t)K2 * COUT * 2 + 256;

    if (ws_size >= need_v5) {
        int*      wsi   = (int*)d_ws;
        int*      gctr1 = wsi;                           // [64]
        int*      gctr2 = wsi + 64;                      // [NF]
        unsigned* gbin1 = (unsigned*)(wsi + ctr_ints);
        unsigned* gbin2 = gbin1 + bin1_recs;
        ushort*   yh    = (ushort*)(gbin2 + bin2_recs);
        ushort*   wb    = yh + yh_elems;
        float*    out   = (float*)d_out;

        hipMemsetAsync(wsi, 0, ctr_ints * sizeof(int), stream);
        k_castw<<<32, 256, 0, stream>>>(wgt, wb);
        k_p1   <<<1296, 256, 0, stream>>>(x, wb, bias, esrc, edst, gctr1, gbin1, yh, out);
        k_p2   <<<NB1 * 16, 256, 0, stream>>>(gctr1, gbin1, gctr2, gbin2);
        k_p3   <<<1563, 256, 0, stream>>>(gctr2, gbin2, yh, out);
    } else {
        int* wsi  = (int*)d_ws;
        int* cnt  = wsi;
        int* csrF = wsi + NN;
        ushort* wb = (ushort*)(wsi + NN + (size_t)NN * CAP);
        ushort* hcat = (ushort*)d_out;

        hipMemsetAsync(cnt, 0, (size_t)NN * sizeof(int), stream);
        k_fuse2<<<NB_SCAT + NB_CAST + NB_CASTW, 256, 0, stream>>>(
            x, wgt, esrc, edst, cnt, csrF, hcat, wb);
        k_aggB <<<NN / 4, 256, 0, stream>>>(cnt, csrF, hcat);
        k_gemm <<<(NN + 127) / 128, 256, 0, stream>>>(hcat, wb, bias, (float*)d_out);
    }
}

// Round 10
// 167.566 us; speedup vs baseline: 7.9918x; 1.0163x over previous
//
#include <hip/hip_runtime.h>

#define NN   100000
#define NE   1600000
#define CIN  128
#define K2   256
#define COUT 128

typedef __attribute__((ext_vector_type(8))) short bf16x8;
typedef __attribute__((ext_vector_type(4))) float f32x4;

__device__ __forceinline__ ushort f2bf(float f) {
    union { float f; unsigned u; } v; v.f = f;
    unsigned r = (v.u + 0x7FFFu + ((v.u >> 16) & 1u)) >> 16;
    return (ushort)r;
}
__device__ __forceinline__ float bflo(unsigned p) {
    union { unsigned u; float f; } v; v.u = p << 16; return v.f;
}
__device__ __forceinline__ float bfhi(unsigned p) {
    union { unsigned u; float f; } v; v.u = p & 0xFFFF0000u; return v.f;
}

// ======================= V6: split phases, single-level bins =======================
// rec = src (bits 0..16) | (dst & 127) << 17 ; bin f = dst>>7 (782 bins of 128 nodes)

#define NBIN     784       // bins allocated (782 used)
#define CAP3     2304      // records per bin (mean 2041, +5.8 sigma)
#define LCAP     8         // LDS staging slots per bin
#define NB_BIN   512       // bin blocks
#define E_BIN    3125      // edges per bin block
#define SRCMASK  0x1FFFF

// ---- W f32 -> bf16 ----
__global__ __launch_bounds__(256) void k_castw(const float* __restrict__ w,
                                               ushort* __restrict__ wb) {
    int i = blockIdx.x * 256 + threadIdx.x;
    float4 v = *reinterpret_cast<const float4*>(w + (size_t)i * 4);
    ushort4 r; r.x = f2bf(v.x); r.y = f2bf(v.y); r.z = f2bf(v.z); r.w = f2bf(v.w);
    *reinterpret_cast<ushort4*>(wb + (size_t)i * 4) = r;
}

// ---- dual GEMM, shared A: yh = x@Wh^T (bf16), out = x@Wx^T + bias (f32) ----
__global__ __launch_bounds__(256) void k_gemm2(const float* __restrict__ x,
                                               const ushort* __restrict__ wb,
                                               const float* __restrict__ bias,
                                               ushort* __restrict__ yh,
                                               float* __restrict__ out) {
    int t = threadIdx.x;
    int wid = t >> 6, lane = t & 63;
    int lr = lane & 15, lk = lane >> 4;
    int row0 = blockIdx.x * 128 + wid * 32;

    f32x4 acch[2][8], accx[2][8];
    #pragma unroll
    for (int m = 0; m < 2; ++m)
        #pragma unroll
        for (int n = 0; n < 8; ++n) { acch[m][n] = (f32x4)0.f; accx[m][n] = (f32x4)0.f; }

    #pragma unroll
    for (int kb = 0; kb < 4; ++kb) {
        int kofs = kb * 32 + lk * 8;
        bf16x8 a[2];
        #pragma unroll
        for (int m = 0; m < 2; ++m) {
            int r = row0 + m * 16 + lr; if (r >= NN) r = NN - 1;
            const float* xp = x + (size_t)r * CIN + kofs;
            float4 u0 = *reinterpret_cast<const float4*>(xp);
            float4 u1 = *reinterpret_cast<const float4*>(xp + 4);
            bf16x8 aa;
            aa[0] = (short)f2bf(u0.x); aa[1] = (short)f2bf(u0.y);
            aa[2] = (short)f2bf(u0.z); aa[3] = (short)f2bf(u0.w);
            aa[4] = (short)f2bf(u1.x); aa[5] = (short)f2bf(u1.y);
            aa[6] = (short)f2bf(u1.z); aa[7] = (short)f2bf(u1.w);
            a[m] = aa;
        }
        #pragma unroll
        for (int n = 0; n < 8; ++n) {
            const ushort* wrow = wb + (size_t)(n * 16 + lr) * K2 + kofs;
            bf16x8 bh = *reinterpret_cast<const bf16x8*>(wrow);         // Wh: k in [0,128)
            bf16x8 bx = *reinterpret_cast<const bf16x8*>(wrow + CIN);   // Wx: k in [128,256)
            acch[0][n] = __builtin_amdgcn_mfma_f32_16x16x32_bf16(a[0], bh, acch[0][n], 0, 0, 0);
            acch[1][n] = __builtin_amdgcn_mfma_f32_16x16x32_bf16(a[1], bh, acch[1][n], 0, 0, 0);
            accx[0][n] = __builtin_amdgcn_mfma_f32_16x16x32_bf16(a[0], bx, accx[0][n], 0, 0, 0);
            accx[1][n] = __builtin_amdgcn_mfma_f32_16x16x32_bf16(a[1], bx, accx[1][n], 0, 0, 0);
        }
    }

    float bv[8];
    #pragma unroll
    for (int n = 0; n < 8; ++n) bv[n] = bias[n * 16 + lr];

    // C/D: col = lane&15, row = (lane>>4)*4 + j
    #pragma unroll
    for (int m = 0; m < 2; ++m)
        #pragma unroll
        for (int j = 0; j < 4; ++j) {
            int r = row0 + m * 16 + lk * 4 + j;
            if (r < NN) {
                #pragma unroll
                for (int n = 0; n < 8; ++n) {
                    yh[(size_t)r * CIN + n * 16 + lr]   = f2bf(acch[m][n][j]);
                    out[(size_t)r * COUT + n * 16 + lr] = accx[m][n][j] + bv[n];
                }
            }
        }
}

// ---- single-level binning: edges -> 782 fine bins, LDS staged ----
__global__ __launch_bounds__(256) void k_bin(const int* __restrict__ esrc,
                                             const int* __restrict__ edst,
                                             int* __restrict__ gctr,
                                             unsigned* __restrict__ gbin) {
    __shared__ unsigned lbuf[NBIN * LCAP];    // 25 KB
    __shared__ int      lcnt[NBIN];           // 3.1 KB
    __shared__ int      lbase[NBIN];          // 3.1 KB
    int b = blockIdx.x, t = threadIdx.x;
    for (int i = t; i < NBIN; i += 256) lcnt[i] = 0;
    __syncthreads();

    int base = b * E_BIN;
    for (int e = t; e < E_BIN; e += 256) {
        int d = edst[base + e], s = esrc[base + e];
        int f = d >> 7;
        unsigned rec = (unsigned)s | ((unsigned)(d & 127) << 17);
        int p = atomicAdd(&lcnt[f], 1);
        if (p < LCAP) lbuf[(f << 3) + p] = rec;
        else {                                 // overflow net (~1% of edges)
            int gp = atomicAdd(&gctr[f], 1);
            if (gp < CAP3) gbin[(size_t)f * CAP3 + gp] = rec;
        }
    }
    __syncthreads();

    // claim global slots (one atomic per non-empty bin)
    for (int f = t; f < NBIN; f += 256) {
        int n = lcnt[f]; if (n > LCAP) n = LCAP;
        lcnt[f] = n;
        lbase[f] = (n > 0) ? atomicAdd(&gctr[f], n) : 0;
    }
    __syncthreads();

    // slot-parallel writeback
    for (int s = t; s < NBIN * LCAP; s += 256) {
        int f = s >> 3, k = s & 7;
        if (k < lcnt[f]) {
            int g0 = lbase[f] + k;
            if (g0 < CAP3) gbin[(size_t)f * CAP3 + g0] = lbuf[s];
        }
    }
}

// ---- p3: LDS counting-sort over 128 nodes, paired gather, f32x4 NT RMW ----
__global__ __launch_bounds__(256) void k_p3(const int* __restrict__ gctr,
                                            const unsigned* __restrict__ gbin,
                                            const ushort* __restrict__ yh,
                                            float* __restrict__ out) {
    __shared__ unsigned lrec[CAP3];           // 9.2 KB
    __shared__ int      ssrc[CAP3];           // 9.2 KB
    __shared__ int      hcnt[128];
    __shared__ int      hbase[128];
    __shared__ int      hcur[128];
    __shared__ int      hsum[2];
    int f = blockIdx.x, t = threadIdx.x;
    int wid = t >> 6, lane = t & 63;

    for (int i = t; i < 128; i += 256) hcnt[i] = 0;
    __syncthreads();

    int m = gctr[f]; if (m > CAP3) m = CAP3;

    // A: stage records + histogram over 128 local nodes
    for (int i = t; i < m; i += 256) {
        unsigned r = gbin[(size_t)f * CAP3 + i];
        lrec[i] = r;
        atomicAdd(&hcnt[(r >> 17) & 127], 1);
    }
    __syncthreads();

    // B: exclusive prefix over 128 counters (waves 0 and 1)
    if (t < 128) {
        int v = hcnt[t];
        int s = v;
        #pragma unroll
        for (int d = 1; d < 64; d <<= 1) {
            int u = __shfl_up(s, d);
            if (lane >= d) s += u;
        }
        hbase[t] = s - v;
        if (lane == 63) hsum[wid] = s;
    }
    __syncthreads();
    if (t < 128) {
        int add = (wid == 1) ? hsum[0] : 0;
        int b2 = hbase[t] + add;
        hbase[t] = b2;
        hcur[t]  = b2;
    }
    __syncthreads();

    // C: scatter srcs into per-node contiguous lists
    for (int i = t; i < m; i += 256) {
        unsigned r = lrec[i];
        int p = atomicAdd(&hcur[(r >> 17) & 127], 1);
        ssrc[p] = (int)(r & SRCMASK);
    }
    __syncthreads();

    // D: each wave handles 32 nodes; wave halves process 2 edges at once
    int node0 = f << 7;
    int half = lane >> 5;
    int chof = (lane & 31) * 4;               // 4 channels per lane
    for (int i = wid * 32; i < wid * 32 + 32; ++i) {
        int n = node0 + i;
        if (n >= NN) break;
        int d0 = hbase[i], dg = hcnt[i];
        float a0 = 0.f, a1 = 0.f, a2 = 0.f, a3 = 0.f;
        for (int e = 0; e < dg; e += 8) {
            #pragma unroll
            for (int q = 0; q < 4; ++q) {
                int idx = e + q * 2 + half;
                uint2 v = make_uint2(0u, 0u);
                if (idx < dg) {
                    int s = ssrc[d0 + idx];
                    v = *reinterpret_cast<const uint2*>(yh + ((size_t)s << 7) + chof);
                }
                a0 += bflo(v.x); a1 += bfhi(v.x);
                a2 += bflo(v.y); a3 += bfhi(v.y);
            }
        }
        a0 += __shfl(a0, lane ^ 32);
        a1 += __shfl(a1, lane ^ 32);
        a2 += __shfl(a2, lane ^ 32);
        a3 += __shfl(a3, lane ^ 32);
        float inv = (dg > 0) ? 1.0f / (float)dg : 0.0f;
        if (lane < 32) {
            f32x4* po = reinterpret_cast<f32x4*>(out + ((size_t)n << 7) + chof);
            f32x4 o = __builtin_nontemporal_load(po);
            o[0] += a0 * inv; o[1] += a1 * inv;
            o[2] += a2 * inv; o[3] += a3 * inv;
            __builtin_nontemporal_store(o, po);
        }
    }
}

// ======================= V2 fallback (round-5, validated) =======================

#define NXCD  8
#define PART  ((NN + NXCD - 1) / NXCD)
#define NB_SCAT  2048
#define NB_CAST  12500
#define NB_CASTW 32
#define CAP  64

__global__ __launch_bounds__(256) void k_fuse2(const float* __restrict__ x,
                                               const float* __restrict__ w,
                                               const int* __restrict__ src,
                                               const int* __restrict__ dst,
                                               int* __restrict__ cnt,
                                               int* __restrict__ csrF,
                                               ushort* hcat,
                                               ushort* __restrict__ wb) {
    int b = blockIdx.x, t = threadIdx.x;
    if (b < NB_SCAT) {
        int part = b & (NXCD - 1);
        int slot = b >> 3;
        int lo = part * PART;
        int hi = lo + PART; if (hi > NN) hi = NN;
        const int NCH = NE / 4;
        for (int c = slot * 256 + t; c < NCH; c += 256 * 256) {
            int4 d = *reinterpret_cast<const int4*>(dst + (size_t)c * 4);
            int4 s = *reinterpret_cast<const int4*>(src + (size_t)c * 4);
            if (d.x >= lo && d.x < hi) { int p = atomicAdd(&cnt[d.x], 1); csrF[(d.x << 6) + p] = s.x; }
            if (d.y >= lo && d.y < hi) { int p = atomicAdd(&cnt[d.y], 1); csrF[(d.y << 6) + p] = s.y; }
            if (d.z >= lo && d.z < hi) { int p = atomicAdd(&cnt[d.z], 1); csrF[(d.z << 6) + p] = s.z; }
            if (d.w >= lo && d.w < hi) { int p = atomicAdd(&cnt[d.w], 1); csrF[(d.w << 6) + p] = s.w; }
        }
    } else if (b < NB_SCAT + NB_CAST) {
        int i = (b - NB_SCAT) * 256 + t;
        int node = i >> 5, c4 = (i & 31) * 4;
        float4 v = *reinterpret_cast<const float4*>(x + (size_t)node * CIN + c4);
        ushort4 r; r.x = f2bf(v.x); r.y = f2bf(v.y); r.z = f2bf(v.z); r.w = f2bf(v.w);
        *reinterpret_cast<ushort4*>(hcat + (size_t)node * K2 + CIN + c4) = r;
    } else {
        int i = (b - NB_SCAT - NB_CAST) * 256 + t;
        float4 v = *reinterpret_cast<const float4*>(w + (size_t)i * 4);
        ushort4 r; r.x = f2bf(v.x); r.y = f2bf(v.y); r.z = f2bf(v.z); r.w = f2bf(v.w);
        *reinterpret_cast<ushort4*>(wb + (size_t)i * 4) = r;
    }
}

__global__ __launch_bounds__(256) void k_aggB(const int* __restrict__ cnt,
                                              const int* __restrict__ csrF,
                                              ushort* hcat) {
    int gw   = (blockIdx.x * 256 + threadIdx.x) >> 6;
    int lane = threadIdx.x & 63;
    if (gw >= NN) return;
    int gws = __builtin_amdgcn_readfirstlane(gw);
    int deg = cnt[gws];
    const int4* b4 = reinterpret_cast<const int4*>(csrF + ((size_t)gws << 6));
    int boff = CIN + lane * 2;
    float ax = 0.f, ay = 0.f;
    for (int e = 0; e < deg; e += 8) {
        int4 c0 = b4[(e >> 2)];
        int4 c1 = b4[(e >> 2) + 1];
        int ss[8] = {c0.x, c0.y, c0.z, c0.w, c1.x, c1.y, c1.z, c1.w};
        #pragma unroll
        for (int k = 0; k < 8; ++k) {
            bool ok = (e + k) < deg;
            int s = ok ? ss[k] : 0;
            unsigned v = *reinterpret_cast<const unsigned*>(hcat + ((size_t)s << 8) + boff);
            float mq = ok ? 1.f : 0.f;
            ax += mq * bflo(v); ay += mq * bfhi(v);
        }
    }
    float inv = (deg > 0) ? 1.0f / (float)deg : 0.0f;
    unsigned packed = (unsigned)f2bf(ax * inv) | ((unsigned)f2bf(ay * inv) << 16);
    *reinterpret_cast<unsigned*>(hcat + ((size_t)gw << 8) + lane * 2) = packed;
}

__global__ __launch_bounds__(256) void k_gemm(const ushort* hcat,
                                              const ushort* __restrict__ wb,
                                              const float* __restrict__ bias,
                                              float* out) {
    int t = threadIdx.x;
    int wid = t >> 6, lane = t & 63;
    int lr = lane & 15, lk = lane >> 4;
    int row0 = blockIdx.x * 128 + wid * 32;

    f32x4 acc[2][8];
    #pragma unroll
    for (int m = 0; m < 2; ++m)
        #pragma unroll
        for (int n = 0; n < 8; ++n) acc[m][n] = (f32x4)0.f;

    #pragma unroll
    for (int kb = 0; kb < 8; ++kb) {
        int kofs = kb * 32 + lk * 8;
        bf16x8 a[2];
        #pragma unroll
        for (int m = 0; m < 2; ++m) {
            int r = row0 + m * 16 + lr; if (r >= NN) r = NN - 1;
            a[m] = *reinterpret_cast<const bf16x8*>(hcat + ((size_t)r << 8) + kofs);
        }
        #pragma unroll
        for (int n = 0; n < 8; ++n) {
            bf16x8 bfr = *reinterpret_cast<const bf16x8*>(wb + (size_t)(n * 16 + lr) * K2 + kofs);
            acc[0][n] = __builtin_amdgcn_mfma_f32_16x16x32_bf16(a[0], bfr, acc[0][n], 0, 0, 0);
            acc[1][n] = __builtin_amdgcn_mfma_f32_16x16x32_bf16(a[1], bfr, acc[1][n], 0, 0, 0);
        }
    }

    float bv[8];
    #pragma unroll
    for (int n = 0; n < 8; ++n) bv[n] = bias[n * 16 + lr];

    #pragma unroll
    for (int m = 0; m < 2; ++m)
        #pragma unroll
        for (int j = 0; j < 4; ++j) {
            int r = row0 + m * 16 + lk * 4 + j;
            if (r < NN) {
                #pragma unroll
                for (int n = 0; n < 8; ++n)
                    out[(size_t)r * COUT + n * 16 + lr] = acc[m][n][j] + bv[n];
            }
        }
}

// ---------------- host ----------------

extern "C" void kernel_launch(void* const* d_in, const int* in_sizes, int n_in,
                              void* d_out, int out_size, void* d_ws, size_t ws_size,
                              hipStream_t stream) {
    (void)in_sizes; (void)n_in; (void)out_size;
    const float* x    = (const float*)d_in[0];
    const int*   esrc = (const int*)  d_in[1];
    const int*   edst = (const int*)  d_in[2];
    const float* wgt  = (const float*)d_in[3];
    const float* bias = (const float*)d_in[4];

    size_t ctr_ints  = 800;                              // NBIN rounded up
    size_t bin_recs  = (size_t)NBIN * CAP3;              // 1,806,336 u32
    size_t yh_elems  = (size_t)NN * CIN;                 // 12.8M ushort
    size_t need_v6 = ctr_ints * 4 + bin_recs * 4
                   + yh_elems * 2 + (size_t)K2 * COUT * 2 + 256;

    if (ws_size >= need_v6) {
        int*      wsi  = (int*)d_ws;
        int*      gctr = wsi;                            // [NBIN]
        unsigned* gbin = (unsigned*)(wsi + ctr_ints);
        ushort*   yh   = (ushort*)(gbin + bin_recs);
        ushort*   wb   = yh + yh_elems;
        float*    out  = (float*)d_out;

        hipMemsetAsync(gctr, 0, ctr_ints * sizeof(int), stream);
        k_castw<<<32, 256, 0, stream>>>(wgt, wb);
        k_bin  <<<NB_BIN, 256, 0, stream>>>(esrc, edst, gctr, gbin);
        k_gemm2<<<784, 256, 0, stream>>>(x, wb, bias, yh, out);
        k_p3   <<<782, 256, 0, stream>>>(gctr, gbin, yh, out);
    } else {
        int* wsi  = (int*)d_ws;
        int* cnt  = wsi;
        int* csrF = wsi + NN;
        ushort* wb = (ushort*)(wsi + NN + (size_t)NN * CAP);
        ushort* hcat = (ushort*)d_out;

        hipMemsetAsync(cnt, 0, (size_t)NN * sizeof(int), stream);
        k_fuse2<<<NB_SCAT + NB_CAST + NB_CASTW, 256, 0, stream>>>(
            x, wgt, esrc, edst, cnt, csrF, hcat, wb);
        k_aggB <<<NN / 4, 256, 0, stream>>>(cnt, csrF, hcat);
        k_gemm <<<(NN + 127) / 128, 256, 0, stream>>>(hcat, wb, bias, (float*)d_out);
    }
}

// Round 11
// 161.015 us; speedup vs baseline: 8.3170x; 1.0407x over previous
//
#include <hip/hip_runtime.h>

#define NN   100000
#define NE   1600000
#define CIN  128
#define K2   256
#define COUT 128

typedef __attribute__((ext_vector_type(8))) short bf16x8;
typedef __attribute__((ext_vector_type(4))) float f32x4;

__device__ __forceinline__ ushort f2bf(float f) {
    union { float f; unsigned u; } v; v.f = f;
    unsigned r = (v.u + 0x7FFFu + ((v.u >> 16) & 1u)) >> 16;
    return (ushort)r;
}
__device__ __forceinline__ float bflo(unsigned p) {
    union { unsigned u; float f; } v; v.u = p << 16; return v.f;
}
__device__ __forceinline__ float bfhi(unsigned p) {
    union { unsigned u; float f; } v; v.u = p & 0xFFFF0000u; return v.f;
}

// ======================= V7: split phases, half-bin p3 blocks =======================
// rec = src (bits 0..16) | (dst & 127) << 17 ; bin f = dst>>7 (782 bins of 128 nodes)

#define NBIN     784       // bins allocated (782 used)
#define CAP3     2304      // records per bin (mean 2041, +5.8 sigma)
#define LCAP     8         // LDS staging slots per bin (k_bin)
#define NB_BIN   512       // bin blocks
#define E_BIN    3125      // edges per bin block
#define SRCMASK  0x1FFFF
#define SCAP     1536      // per-half-bin src list cap (mean 1024, +16 sigma)

// ---- W f32 -> bf16 (blocks 0-31) + gctr zeroing (block 32) ----
__global__ __launch_bounds__(256) void k_castw(const float* __restrict__ w,
                                               ushort* __restrict__ wb,
                                               int* __restrict__ gctr) {
    int t = threadIdx.x;
    if (blockIdx.x < 32) {
        int i = blockIdx.x * 256 + t;
        float4 v = *reinterpret_cast<const float4*>(w + (size_t)i * 4);
        ushort4 r; r.x = f2bf(v.x); r.y = f2bf(v.y); r.z = f2bf(v.z); r.w = f2bf(v.w);
        *reinterpret_cast<ushort4*>(wb + (size_t)i * 4) = r;
    } else {
        for (int i = t; i < NBIN + 16; i += 256) gctr[i] = 0;
    }
}

// ---- dual GEMM, shared A: yh = x@Wh^T (bf16), out = x@Wx^T + bias (f32) ----
__global__ __launch_bounds__(256) void k_gemm2(const float* __restrict__ x,
                                               const ushort* __restrict__ wb,
                                               const float* __restrict__ bias,
                                               ushort* __restrict__ yh,
                                               float* __restrict__ out) {
    int t = threadIdx.x;
    int wid = t >> 6, lane = t & 63;
    int lr = lane & 15, lk = lane >> 4;
    int row0 = blockIdx.x * 128 + wid * 32;

    f32x4 acch[2][8], accx[2][8];
    #pragma unroll
    for (int m = 0; m < 2; ++m)
        #pragma unroll
        for (int n = 0; n < 8; ++n) { acch[m][n] = (f32x4)0.f; accx[m][n] = (f32x4)0.f; }

    #pragma unroll
    for (int kb = 0; kb < 4; ++kb) {
        int kofs = kb * 32 + lk * 8;
        bf16x8 a[2];
        #pragma unroll
        for (int m = 0; m < 2; ++m) {
            int r = row0 + m * 16 + lr; if (r >= NN) r = NN - 1;
            const float* xp = x + (size_t)r * CIN + kofs;
            float4 u0 = *reinterpret_cast<const float4*>(xp);
            float4 u1 = *reinterpret_cast<const float4*>(xp + 4);
            bf16x8 aa;
            aa[0] = (short)f2bf(u0.x); aa[1] = (short)f2bf(u0.y);
            aa[2] = (short)f2bf(u0.z); aa[3] = (short)f2bf(u0.w);
            aa[4] = (short)f2bf(u1.x); aa[5] = (short)f2bf(u1.y);
            aa[6] = (short)f2bf(u1.z); aa[7] = (short)f2bf(u1.w);
            a[m] = aa;
        }
        #pragma unroll
        for (int n = 0; n < 8; ++n) {
            const ushort* wrow = wb + (size_t)(n * 16 + lr) * K2 + kofs;
            bf16x8 bh = *reinterpret_cast<const bf16x8*>(wrow);         // Wh: k in [0,128)
            bf16x8 bx = *reinterpret_cast<const bf16x8*>(wrow + CIN);   // Wx: k in [128,256)
            acch[0][n] = __builtin_amdgcn_mfma_f32_16x16x32_bf16(a[0], bh, acch[0][n], 0, 0, 0);
            acch[1][n] = __builtin_amdgcn_mfma_f32_16x16x32_bf16(a[1], bh, acch[1][n], 0, 0, 0);
            accx[0][n] = __builtin_amdgcn_mfma_f32_16x16x32_bf16(a[0], bx, accx[0][n], 0, 0, 0);
            accx[1][n] = __builtin_amdgcn_mfma_f32_16x16x32_bf16(a[1], bx, accx[1][n], 0, 0, 0);
        }
    }

    float bv[8];
    #pragma unroll
    for (int n = 0; n < 8; ++n) bv[n] = bias[n * 16 + lr];

    #pragma unroll
    for (int m = 0; m < 2; ++m)
        #pragma unroll
        for (int j = 0; j < 4; ++j) {
            int r = row0 + m * 16 + lk * 4 + j;
            if (r < NN) {
                #pragma unroll
                for (int n = 0; n < 8; ++n) {
                    yh[(size_t)r * CIN + n * 16 + lr]   = f2bf(acch[m][n][j]);
                    out[(size_t)r * COUT + n * 16 + lr] = accx[m][n][j] + bv[n];
                }
            }
        }
}

// ---- single-level binning: edges -> 782 fine bins, LDS staged ----
__global__ __launch_bounds__(256) void k_bin(const int* __restrict__ esrc,
                                             const int* __restrict__ edst,
                                             int* __restrict__ gctr,
                                             unsigned* __restrict__ gbin) {
    __shared__ unsigned lbuf[NBIN * LCAP];    // 25 KB
    __shared__ int      lcnt[NBIN];
    __shared__ int      lbase[NBIN];
    int b = blockIdx.x, t = threadIdx.x;
    for (int i = t; i < NBIN; i += 256) lcnt[i] = 0;
    __syncthreads();

    int base = b * E_BIN;
    for (int e = t; e < E_BIN; e += 256) {
        int d = edst[base + e], s = esrc[base + e];
        int f = d >> 7;
        unsigned rec = (unsigned)s | ((unsigned)(d & 127) << 17);
        int p = atomicAdd(&lcnt[f], 1);
        if (p < LCAP) lbuf[(f << 3) + p] = rec;
        else {
            int gp = atomicAdd(&gctr[f], 1);
            if (gp < CAP3) gbin[(size_t)f * CAP3 + gp] = rec;
        }
    }
    __syncthreads();

    for (int f = t; f < NBIN; f += 256) {
        int n = lcnt[f]; if (n > LCAP) n = LCAP;
        lcnt[f] = n;
        lbase[f] = (n > 0) ? atomicAdd(&gctr[f], n) : 0;
    }
    __syncthreads();

    for (int s = t; s < NBIN * LCAP; s += 256) {
        int f = s >> 3, k = s & 7;
        if (k < lcnt[f]) {
            int g0 = lbase[f] + k;
            if (g0 < CAP3) gbin[(size_t)f * CAP3 + g0] = lbuf[s];
        }
    }
}

// ---- p3: half-bin blocks (64 nodes), 2-pass global sort, paired gather ----
__global__ __launch_bounds__(256) void k_p3(const int* __restrict__ gctr,
                                            const unsigned* __restrict__ gbin,
                                            const ushort* __restrict__ yh,
                                            float* __restrict__ out) {
    __shared__ int ssrc[SCAP];                // 6 KB
    __shared__ int hcnt[64];
    __shared__ int hbase[64];
    __shared__ int hcur[64];
    int f   = blockIdx.x >> 1;                // bin
    int sub = blockIdx.x & 1;                 // node half
    int t = threadIdx.x;
    int wid = t >> 6, lane = t & 63;

    if (t < 64) hcnt[t] = 0;
    __syncthreads();

    int m = gctr[f]; if (m > CAP3) m = CAP3;
    const unsigned* recs = gbin + (size_t)f * CAP3;

    // A: histogram my half's nodes (read 1)
    for (int i = t; i < m; i += 256) {
        unsigned r = recs[i];
        int node = (r >> 17) & 127;
        if ((node >> 6) == sub) atomicAdd(&hcnt[node & 63], 1);
    }
    __syncthreads();

    // B: exclusive prefix over 64 counters (wave 0)
    if (t < 64) {
        int v = hcnt[t];
        int s = v;
        #pragma unroll
        for (int d = 1; d < 64; d <<= 1) {
            int u = __shfl_up(s, d);
            if (lane >= d) s += u;
        }
        hbase[t] = s - v;
        hcur[t]  = s - v;
    }
    __syncthreads();

    // C: scatter srcs into per-node contiguous lists (read 2, L2-hot)
    for (int i = t; i < m; i += 256) {
        unsigned r = recs[i];
        int node = (r >> 17) & 127;
        if ((node >> 6) == sub) {
            int p = atomicAdd(&hcur[node & 63], 1);
            if (p < SCAP) ssrc[p] = (int)(r & SRCMASK);
        }
    }
    __syncthreads();

    // D: each wave handles 16 nodes; wave halves process 2 edges at once
    int node0 = (f << 7) + (sub << 6);
    int half = lane >> 5;
    int chof = (lane & 31) * 4;               // 4 channels per lane
    for (int i = wid * 16; i < wid * 16 + 16; ++i) {
        int n = node0 + i;
        if (n >= NN) break;
        int d0 = hbase[i], dg = hcnt[i];
        float a0 = 0.f, a1 = 0.f, a2 = 0.f, a3 = 0.f;
        for (int e = 0; e < dg; e += 8) {
            #pragma unroll
            for (int q = 0; q < 4; ++q) {
                int idx = e + q * 2 + half;
                uint2 v = make_uint2(0u, 0u);
                if (idx < dg) {
                    int s = ssrc[d0 + idx];
                    v = *reinterpret_cast<const uint2*>(yh + ((size_t)s << 7) + chof);
                }
                a0 += bflo(v.x); a1 += bfhi(v.x);
                a2 += bflo(v.y); a3 += bfhi(v.y);
            }
        }
        a0 += __shfl(a0, lane ^ 32);
        a1 += __shfl(a1, lane ^ 32);
        a2 += __shfl(a2, lane ^ 32);
        a3 += __shfl(a3, lane ^ 32);
        float inv = (dg > 0) ? 1.0f / (float)dg : 0.0f;
        if (lane < 32) {
            f32x4* po = reinterpret_cast<f32x4*>(out + ((size_t)n << 7) + chof);
            f32x4 o = __builtin_nontemporal_load(po);
            o[0] += a0 * inv; o[1] += a1 * inv;
            o[2] += a2 * inv; o[3] += a3 * inv;
            __builtin_nontemporal_store(o, po);
        }
    }
}

// ======================= V2 fallback (round-5, validated) =======================

#define NXCD  8
#define PART  ((NN + NXCD - 1) / NXCD)
#define NB_SCAT  2048
#define NB_CAST  12500
#define NB_CASTW 32
#define CAP  64

__global__ __launch_bounds__(256) void k_fuse2(const float* __restrict__ x,
                                               const float* __restrict__ w,
                                               const int* __restrict__ src,
                                               const int* __restrict__ dst,
                                               int* __restrict__ cnt,
                                               int* __restrict__ csrF,
                                               ushort* hcat,
                                               ushort* __restrict__ wb) {
    int b = blockIdx.x, t = threadIdx.x;
    if (b < NB_SCAT) {
        int part = b & (NXCD - 1);
        int slot = b >> 3;
        int lo = part * PART;
        int hi = lo + PART; if (hi > NN) hi = NN;
        const int NCH = NE / 4;
        for (int c = slot * 256 + t; c < NCH; c += 256 * 256) {
            int4 d = *reinterpret_cast<const int4*>(dst + (size_t)c * 4);
            int4 s = *reinterpret_cast<const int4*>(src + (size_t)c * 4);
            if (d.x >= lo && d.x < hi) { int p = atomicAdd(&cnt[d.x], 1); csrF[(d.x << 6) + p] = s.x; }
            if (d.y >= lo && d.y < hi) { int p = atomicAdd(&cnt[d.y], 1); csrF[(d.y << 6) + p] = s.y; }
            if (d.z >= lo && d.z < hi) { int p = atomicAdd(&cnt[d.z], 1); csrF[(d.z << 6) + p] = s.z; }
            if (d.w >= lo && d.w < hi) { int p = atomicAdd(&cnt[d.w], 1); csrF[(d.w << 6) + p] = s.w; }
        }
    } else if (b < NB_SCAT + NB_CAST) {
        int i = (b - NB_SCAT) * 256 + t;
        int node = i >> 5, c4 = (i & 31) * 4;
        float4 v = *reinterpret_cast<const float4*>(x + (size_t)node * CIN + c4);
        ushort4 r; r.x = f2bf(v.x); r.y = f2bf(v.y); r.z = f2bf(v.z); r.w = f2bf(v.w);
        *reinterpret_cast<ushort4*>(hcat + (size_t)node * K2 + CIN + c4) = r;
    } else {
        int i = (b - NB_SCAT - NB_CAST) * 256 + t;
        float4 v = *reinterpret_cast<const float4*>(w + (size_t)i * 4);
        ushort4 r; r.x = f2bf(v.x); r.y = f2bf(v.y); r.z = f2bf(v.z); r.w = f2bf(v.w);
        *reinterpret_cast<ushort4*>(wb + (size_t)i * 4) = r;
    }
}

__global__ __launch_bounds__(256) void k_aggB(const int* __restrict__ cnt,
                                              const int* __restrict__ csrF,
                                              ushort* hcat) {
    int gw   = (blockIdx.x * 256 + threadIdx.x) >> 6;
    int lane = threadIdx.x & 63;
    if (gw >= NN) return;
    int gws = __builtin_amdgcn_readfirstlane(gw);
    int deg = cnt[gws];
    const int4* b4 = reinterpret_cast<const int4*>(csrF + ((size_t)gws << 6));
    int boff = CIN + lane * 2;
    float ax = 0.f, ay = 0.f;
    for (int e = 0; e < deg; e += 8) {
        int4 c0 = b4[(e >> 2)];
        int4 c1 = b4[(e >> 2) + 1];
        int ss[8] = {c0.x, c0.y, c0.z, c0.w, c1.x, c1.y, c1.z, c1.w};
        #pragma unroll
        for (int k = 0; k < 8; ++k) {
            bool ok = (e + k) < deg;
            int s = ok ? ss[k] : 0;
            unsigned v = *reinterpret_cast<const unsigned*>(hcat + ((size_t)s << 8) + boff);
            float mq = ok ? 1.f : 0.f;
            ax += mq * bflo(v); ay += mq * bfhi(v);
        }
    }
    float inv = (deg > 0) ? 1.0f / (float)deg : 0.0f;
    unsigned packed = (unsigned)f2bf(ax * inv) | ((unsigned)f2bf(ay * inv) << 16);
    *reinterpret_cast<unsigned*>(hcat + ((size_t)gw << 8) + lane * 2) = packed;
}

__global__ __launch_bounds__(256) void k_gemm(const ushort* hcat,
                                              const ushort* __restrict__ wb,
                                              const float* __restrict__ bias,
                                              float* out) {
    int t = threadIdx.x;
    int wid = t >> 6, lane = t & 63;
    int lr = lane & 15, lk = lane >> 4;
    int row0 = blockIdx.x * 128 + wid * 32;

    f32x4 acc[2][8];
    #pragma unroll
    for (int m = 0; m < 2; ++m)
        #pragma unroll
        for (int n = 0; n < 8; ++n) acc[m][n] = (f32x4)0.f;

    #pragma unroll
    for (int kb = 0; kb < 8; ++kb) {
        int kofs = kb * 32 + lk * 8;
        bf16x8 a[2];
        #pragma unroll
        for (int m = 0; m < 2; ++m) {
            int r = row0 + m * 16 + lr; if (r >= NN) r = NN - 1;
            a[m] = *reinterpret_cast<const bf16x8*>(hcat + ((size_t)r << 8) + kofs);
        }
        #pragma unroll
        for (int n = 0; n < 8; ++n) {
            bf16x8 bfr = *reinterpret_cast<const bf16x8*>(wb + (size_t)(n * 16 + lr) * K2 + kofs);
            acc[0][n] = __builtin_amdgcn_mfma_f32_16x16x32_bf16(a[0], bfr, acc[0][n], 0, 0, 0);
            acc[1][n] = __builtin_amdgcn_mfma_f32_16x16x32_bf16(a[1], bfr, acc[1][n], 0, 0, 0);
        }
    }

    float bv[8];
    #pragma unroll
    for (int n = 0; n < 8; ++n) bv[n] = bias[n * 16 + lr];

    #pragma unroll
    for (int m = 0; m < 2; ++m)
        #pragma unroll
        for (int j = 0; j < 4; ++j) {
            int r = row0 + m * 16 + lk * 4 + j;
            if (r < NN) {
                #pragma unroll
                for (int n = 0; n < 8; ++n)
                    out[(size_t)r * COUT + n * 16 + lr] = acc[m][n][j] + bv[n];
            }
        }
}

// ---------------- host ----------------

extern "C" void kernel_launch(void* const* d_in, const int* in_sizes, int n_in,
                              void* d_out, int out_size, void* d_ws, size_t ws_size,
                              hipStream_t stream) {
    (void)in_sizes; (void)n_in; (void)out_size;
    const float* x    = (const float*)d_in[0];
    const int*   esrc = (const int*)  d_in[1];
    const int*   edst = (const int*)  d_in[2];
    const float* wgt  = (const float*)d_in[3];
    const float* bias = (const float*)d_in[4];

    size_t ctr_ints  = 800;                              // NBIN rounded up
    size_t bin_recs  = (size_t)NBIN * CAP3;              // 1,806,336 u32
    size_t yh_elems  = (size_t)NN * CIN;                 // 12.8M ushort
    size_t need_v7 = ctr_ints * 4 + bin_recs * 4
                   + yh_elems * 2 + (size_t)K2 * COUT * 2 + 256;

    if (ws_size >= need_v7) {
        int*      wsi  = (int*)d_ws;
        int*      gctr = wsi;                            // [NBIN]
        unsigned* gbin = (unsigned*)(wsi + ctr_ints);
        ushort*   yh   = (ushort*)(gbin + bin_recs);
        ushort*   wb   = yh + yh_elems;
        float*    out  = (float*)d_out;

        k_castw<<<33, 256, 0, stream>>>(wgt, wb, gctr);  // cast + gctr zero
        k_bin  <<<NB_BIN, 256, 0, stream>>>(esrc, edst, gctr, gbin);
        k_gemm2<<<784, 256, 0, stream>>>(x, wb, bias, yh, out);
        k_p3   <<<NBIN * 2, 256, 0, stream>>>(gctr, gbin, yh, out);
    } else {
        int* wsi  = (int*)d_ws;
        int* cnt  = wsi;
        int* csrF = wsi + NN;
        ushort* wb = (ushort*)(wsi + NN + (size_t)NN * CAP);
        ushort* hcat = (ushort*)d_out;

        hipMemsetAsync(cnt, 0, (size_t)NN * sizeof(int), stream);
        k_fuse2<<<NB_SCAT + NB_CAST + NB_CASTW, 256, 0, stream>>>(
            x, wgt, esrc, edst, cnt, csrF, hcat, wb);
        k_aggB <<<NN / 4, 256, 0, stream>>>(cnt, csrF, hcat);
        k_gemm <<<(NN + 127) / 128, 256, 0, stream>>>(hcat, wb, bias, (float*)d_out);
    }
}